// Round 1
// baseline (26040.128 us; speedup 1.0000x reference)
//
#include <hip/hip_runtime.h>
#include <hip/hip_bf16.h>

typedef unsigned short ushort_t;
typedef unsigned int uint_t;

#define NN    10000
#define NE    320000
#define NL    4
#define NBLK  1250      // NE / 256 exactly

// ---- workspace float offsets -------------------------------------------------
// coord lives directly in d_out (fp32, 30000 elems, fully initialized by node_init)
#define OFF_FIELD 0        // 30000
#define OFF_HH    30000    // 640000
#define OFF_CSUM  670000   // 30000  (contiguous with MAGG for one memset)
#define OFF_MAGG  700000   // 640000 -> float end 1340000
// ---- int region (starts at float offset 1340000) ----------------------------
#define IOFF_CNTI   0        // 10000
#define IOFF_OFF    10000    // 10001
#define IOFF_CURSOR 20001    // 10000
#define IOFF_PERM   30001    // 320000 -> int end 350001 (total ws ~6.76 MB)

__device__ __forceinline__ float silu(float x) {
    return x / (1.0f + __expf(-x));
}
// fp32 -> bf16 round-to-nearest-even
__device__ __forceinline__ ushort_t f2bf(float f) {
    union { float f; uint_t u; } v; v.f = f;
    const uint_t r = (v.u + 0x7FFFu + ((v.u >> 16) & 1u)) >> 16;
    return (ushort_t)r;
}
__device__ __forceinline__ void unpack2(uint_t p, float& lo, float& hi) {
    union { uint_t u; float f; } a, b;
    a.u = p << 16; b.u = p & 0xffff0000u;
    lo = a.f; hi = b.f;
}

// ---- CSR build: per-row int counts ------------------------------------------
__global__ __launch_bounds__(256) void counti_kernel(const int* __restrict__ rows,
                                                     int* __restrict__ cnti) {
    const int e = blockIdx.x * 256 + threadIdx.x;
    if (e < NE) {
        int r = rows[e];
        r = ((uint_t)r < (uint_t)NN) ? r : 0;
        atomicAdd(&cnti[r], 1);
    }
}

// ---- CSR build: exclusive scan over 10000 counts (single block) --------------
__global__ __launch_bounds__(1024) void scan_kernel(const int* __restrict__ cnti,
                                                    int* __restrict__ off,
                                                    int* __restrict__ cursor) {
    __shared__ int part[1024];
    const int t = threadIdx.x;
    const int base = t * 10;
    int loc[10];
    int s = 0;
    #pragma unroll
    for (int i = 0; i < 10; i++) {
        const int idx = base + i;
        const int v = (idx < NN) ? cnti[idx] : 0;
        loc[i] = s; s += v;
    }
    part[t] = s;
    __syncthreads();
    const int own = s;
    for (int d = 1; d < 1024; d <<= 1) {
        const int v = (t >= d) ? part[t - d] : 0;
        __syncthreads();
        part[t] += v;
        __syncthreads();
    }
    const int excl = part[t] - own;
    #pragma unroll
    for (int i = 0; i < 10; i++) {
        const int idx = base + i;
        if (idx < NN) { const int o = excl + loc[i]; off[idx] = o; cursor[idx] = o; }
    }
    if (t == 0) off[NN] = NE;
}

// ---- CSR build: scatter edge ids into row-sorted order -----------------------
__global__ __launch_bounds__(256) void scatter_kernel(const int* __restrict__ rows,
                                                      int* __restrict__ cursor,
                                                      int* __restrict__ perm) {
    const int e = blockIdx.x * 256 + threadIdx.x;
    if (e < NE) {
        int r = rows[e];
        r = ((uint_t)r < (uint_t)NN) ? r : 0;
        const int pos = atomicAdd(&cursor[r], 1);
        if ((uint_t)pos < (uint_t)NE) perm[pos] = e;
    }
}

// ---- field network + node embedding + coord init (once per call) ------------
__global__ __launch_bounds__(256) void node_init(
    const float* __restrict__ hsrc, const float* __restrict__ xsrc,
    const float* __restrict__ vsrc, const int* __restrict__ charges,
    const float* __restrict__ cls,
    const float* __restrict__ fW1, const float* __restrict__ fb1,
    const float* __restrict__ fW2, const float* __restrict__ fb2,
    const float* __restrict__ fW3, const float* __restrict__ fb3,
    const float* __restrict__ embW, const float* __restrict__ embb,
    float* __restrict__ coord, float* __restrict__ field, float* __restrict__ hh)
{
    __shared__ float sFW1[704], sFW2[1024], sFW3[96];
    __shared__ float sFB1[32], sFB2[32], sFB3[3], sCLS[32], sEW[64], sEB[64];
    const int t = threadIdx.x;
    for (int i = t; i < 704; i += 256) sFW1[i] = fW1[i];
    for (int i = t; i < 1024; i += 256) sFW2[i] = fW2[i];
    if (t < 96) sFW3[t] = fW3[t];
    if (t < 32) { sFB1[t] = fb1[t]; sFB2[t] = fb2[t]; sCLS[t] = cls[t]; }
    if (t < 3)  sFB3[t] = fb3[t];
    if (t < 64) { sEW[t] = embW[t]; sEB[t] = embb[t]; }
    __syncthreads();

    const int n = blockIdx.x * 256 + t;
    if (n >= NN) return;

    float fin[22];
    #pragma unroll
    for (int d = 0; d < 3; d++) {
        fin[d]     = xsrc[3 * n + d];
        fin[3 + d] = vsrc[3 * n + d];
        coord[3 * n + d] = fin[d];
    }
    int ci = charges[n];
    ci = ((uint_t)ci < 2u) ? ci : 0;
    const int cix = ci * 16;
    #pragma unroll
    for (int k = 0; k < 16; k++) fin[6 + k] = sCLS[cix + k];

    float h1[32];
    #pragma unroll
    for (int j = 0; j < 32; j++) h1[j] = sFB1[j];
    #pragma unroll
    for (int k = 0; k < 22; k++) {
        const float v = fin[k];
        #pragma unroll
        for (int j = 0; j < 32; j++) h1[j] += v * sFW1[k * 32 + j];
    }
    #pragma unroll
    for (int j = 0; j < 32; j++) h1[j] = silu(h1[j]);

    float h2[32];
    #pragma unroll
    for (int j = 0; j < 32; j++) h2[j] = sFB2[j];
    #pragma unroll
    for (int k = 0; k < 32; k++) {
        const float v = h1[k];
        #pragma unroll
        for (int j = 0; j < 32; j++) h2[j] += v * sFW2[k * 32 + j];
    }
    #pragma unroll
    for (int j = 0; j < 32; j++) h2[j] = silu(h2[j]);

    #pragma unroll
    for (int d = 0; d < 3; d++) {
        float s = sFB3[d];
        #pragma unroll
        for (int j = 0; j < 32; j++) s += h2[j] * sFW3[j * 3 + d];
        field[3 * n + d] = s;
    }

    const float hv = hsrc[n];
    #pragma unroll
    for (int j = 0; j < 64; j++) hh[(size_t)n * 64 + j] = hv * sEW[j] + sEB[j];
}

// ---- per-layer edge kernel: sorted edges + LDS segmented reduction -----------
// LDS: sW1 bf16 16768 + sW2 fp32 16384 + sCW1 bf16 8192 + biases 1024
//    + tile 16384 + srow 1024 + sscan 1024 + segstart 1028 + snseg 4 = 62832 B
// NOTE: every private array access must be compile-time indexed (rule #20) —
// the previous version's un-unrolled ch0 loop demoted m[64] to scratch and
// generated ~1.4 GB/dispatch of HBM scratch traffic.
__global__ __launch_bounds__(256, 2) void edge_kernel(
    const int* __restrict__ rows, const int* __restrict__ cols,
    const int* __restrict__ perm,
    const float* __restrict__ coord, const float* __restrict__ hh,
    const float* __restrict__ eattr,
    const float* __restrict__ gEW1, const float* __restrict__ gEB1,
    const float* __restrict__ gEW2, const float* __restrict__ gEB2,
    const float* __restrict__ gCW1, const float* __restrict__ gCB1,
    const float* __restrict__ gCW2,
    float* __restrict__ csum, float* __restrict__ magg)
{
    __shared__ __align__(16) ushort_t sW1[131 * 64];   // bf16
    __shared__ __align__(16) float    sW2[64 * 64];    // fp32
    __shared__ __align__(16) ushort_t sCW1[64 * 64];   // bf16
    __shared__ float sB1[64], sB2[64], sCB1[64], sCW2v[64];
    __shared__ float tile[256 * 16];
    __shared__ int   srow[256];
    __shared__ int   sscan[256];
    __shared__ int   segstart[257];
    __shared__ int   snseg;

    const int t = threadIdx.x;
    for (int i = t; i < 2096; i += 256) {          // 131*64 = 8384 = 2096 float4
        const float4 v = ((const float4*)gEW1)[i];
        sW1[4 * i + 0] = f2bf(v.x); sW1[4 * i + 1] = f2bf(v.y);
        sW1[4 * i + 2] = f2bf(v.z); sW1[4 * i + 3] = f2bf(v.w);
    }
    for (int i = t; i < 1024; i += 256) ((float4*)sW2)[i] = ((const float4*)gEW2)[i];
    for (int i = t; i < 1024; i += 256) {          // 64*64 = 4096 = 1024 float4
        const float4 v = ((const float4*)gCW1)[i];
        sCW1[4 * i + 0] = f2bf(v.x); sCW1[4 * i + 1] = f2bf(v.y);
        sCW1[4 * i + 2] = f2bf(v.z); sCW1[4 * i + 3] = f2bf(v.w);
    }
    if (t < 64) { sB1[t] = gEB1[t]; sB2[t] = gEB2[t];
                  sCB1[t] = gCB1[t]; sCW2v[t] = gCW2[t]; }

    const int ep = blockIdx.x * 256 + t;           // NE = 1250*256 exactly, no tail
    int e = perm[ep];
    e = ((uint_t)e < (uint_t)NE) ? e : 0;
    int r = rows[e], c = cols[e];
    r = ((uint_t)r < (uint_t)NN) ? r : 0;
    c = ((uint_t)c < (uint_t)NN) ? c : 0;
    srow[t] = r;
    __syncthreads();

    // block-level segment boundaries over sorted rows
    const int flag = (t == 0) ? 1 : ((srow[t] != srow[t - 1]) ? 1 : 0);
    sscan[t] = flag;
    __syncthreads();
    for (int d = 1; d < 256; d <<= 1) {
        const int v = (t >= d) ? sscan[t - d] : 0;
        __syncthreads();
        sscan[t] += v;
        __syncthreads();
    }
    const int lr = sscan[t] - 1;
    if (flag) segstart[lr] = t;
    if (t == 255) snseg = sscan[255];
    __syncthreads();
    const int nseg = snseg;
    if (t == 0) segstart[nseg] = 256;
    // (next __syncthreads before tile use covers this write)

    // ---- edge MLP ----
    const float dx = coord[3 * r + 0] - coord[3 * c + 0];
    const float dy = coord[3 * r + 1] - coord[3 * c + 1];
    const float dz = coord[3 * r + 2] - coord[3 * c + 2];
    const float radial = dx * dx + dy * dy + dz * dz;
    const float2 ea = ((const float2*)eattr)[e];

    float acc[64];
    #pragma unroll
    for (int j = 0; j < 64; j++) acc[j] = sB1[j];

    const float4* hr4 = (const float4*)(hh + (size_t)r * 64);
    const float4* hc4 = (const float4*)(hh + (size_t)c * 64);
    #pragma unroll 2
    for (int kk = 0; kk < 16; kk++) {
        const float4 a = hr4[kk];
        const float av[4] = {a.x, a.y, a.z, a.w};
        #pragma unroll
        for (int u = 0; u < 4; u++) {
            const float v = av[u];
            const uint_t* w = (const uint_t*)&sW1[(kk * 4 + u) * 64];
            #pragma unroll
            for (int j2 = 0; j2 < 32; j2++) {
                float lo, hi; unpack2(w[j2], lo, hi);
                acc[2 * j2]     += v * lo;
                acc[2 * j2 + 1] += v * hi;
            }
        }
    }
    #pragma unroll 2
    for (int kk = 0; kk < 16; kk++) {
        const float4 a = hc4[kk];
        const float av[4] = {a.x, a.y, a.z, a.w};
        #pragma unroll
        for (int u = 0; u < 4; u++) {
            const float v = av[u];
            const uint_t* w = (const uint_t*)&sW1[(64 + kk * 4 + u) * 64];
            #pragma unroll
            for (int j2 = 0; j2 < 32; j2++) {
                float lo, hi; unpack2(w[j2], lo, hi);
                acc[2 * j2]     += v * lo;
                acc[2 * j2 + 1] += v * hi;
            }
        }
    }
    {
        const float ext[3] = {radial, ea.x, ea.y};
        #pragma unroll
        for (int x = 0; x < 3; x++) {
            const float v = ext[x];
            const uint_t* w = (const uint_t*)&sW1[(128 + x) * 64];
            #pragma unroll
            for (int j2 = 0; j2 < 32; j2++) {
                float lo, hi; unpack2(w[j2], lo, hi);
                acc[2 * j2]     += v * lo;
                acc[2 * j2 + 1] += v * hi;
            }
        }
    }
    #pragma unroll
    for (int j = 0; j < 64; j++) acc[j] = silu(acc[j]);

    // ---- m = silu(acc @ W2 + b2) ----
    // peak live here: acc[64] + m[64]; acc[k] dies after its k iteration.
    float m[64];
    #pragma unroll
    for (int j = 0; j < 64; j++) m[j] = sB2[j];
    #pragma unroll
    for (int k = 0; k < 64; k++) {
        const float v = acc[k];
        const float* w = &sW2[k * 64];
        #pragma unroll
        for (int j = 0; j < 64; j++) m[j] += v * w[j];
    }
    #pragma unroll
    for (int j = 0; j < 64; j++) m[j] = silu(m[j]);

    // ---- cw = silu(m @ cW1 + cb1) @ cW2, chunked 4x16 to cap live regs ----
    float cw = 0.f;
    #pragma unroll
    for (int c4 = 0; c4 < 4; c4++) {
        float chv[16];
        #pragma unroll
        for (int j = 0; j < 16; j++) chv[j] = sCB1[c4 * 16 + j];
        #pragma unroll
        for (int k = 0; k < 64; k++) {
            const float v = m[k];
            const uint_t* w = (const uint_t*)&sCW1[k * 64];
            #pragma unroll
            for (int j2 = 0; j2 < 8; j2++) {
                float lo, hi; unpack2(w[c4 * 8 + j2], lo, hi);
                chv[2 * j2]     += v * lo;
                chv[2 * j2 + 1] += v * hi;
            }
        }
        #pragma unroll
        for (int j = 0; j < 16; j++) cw += silu(chv[j]) * sCW2v[c4 * 16 + j];
    }

    // ---- segmented reduction: magg (4 chunks of 16 channels) ----
    // MUST be fully unrolled so m[] stays compile-time-indexed (registers).
    #pragma unroll
    for (int ch0 = 0; ch0 < 64; ch0 += 16) {
        __syncthreads();
        #pragma unroll
        for (int cc = 0; cc < 16; cc++) tile[t * 16 + cc] = m[ch0 + cc];
        __syncthreads();
        for (int w = t; w < nseg * 16; w += 256) {
            const int lr2 = w >> 4, cc = w & 15;
            const int p0 = segstart[lr2], p1 = segstart[lr2 + 1];
            float s = 0.f;
            for (int p = p0; p < p1; p++) s += tile[p * 16 + cc];
            atomicAdd(&magg[(size_t)srow[p0] * 64 + ch0 + cc], s);
        }
    }

    // ---- segmented reduction: csum (3 channels) ----
    __syncthreads();
    tile[t * 16 + 0] = dx * cw;
    tile[t * 16 + 1] = dy * cw;
    tile[t * 16 + 2] = dz * cw;
    __syncthreads();
    for (int w = t; w < nseg * 3; w += 256) {
        const int lr2 = w / 3, cc = w - lr2 * 3;
        const int p0 = segstart[lr2], p1 = segstart[lr2 + 1];
        float s = 0.f;
        for (int p = p0; p < p1; p++) s += tile[p * 16 + cc];
        atomicAdd(&csum[3 * srow[p0] + cc], s);
    }
}

// ---- per-layer node kernel (vw/gw sequential + chunked output: low reg peak) -
__global__ __launch_bounds__(256, 2) void node_kernel(
    const float* __restrict__ gVW1, const float* __restrict__ gVB1,
    const float* __restrict__ gVW2, const float* __restrict__ gVB2,
    const float* __restrict__ gGW1, const float* __restrict__ gGB1,
    const float* __restrict__ gGW2, const float* __restrict__ gGB2,
    const float* __restrict__ gNW1, const float* __restrict__ gNB1,
    const float* __restrict__ gNW2, const float* __restrict__ gNB2,
    const float* __restrict__ csum, const int* __restrict__ off,
    const float* __restrict__ vsrc, const float* __restrict__ field,
    const float* __restrict__ magg,
    float* __restrict__ coord, float* __restrict__ hh)
{
    __shared__ __align__(16) float sNW1[128 * 64];
    __shared__ __align__(16) float sNW2[64 * 64];
    __shared__ float sNB1[64], sNB2[64];

    const int t = threadIdx.x;
    for (int i = t; i < 2048; i += 256) ((float4*)sNW1)[i] = ((const float4*)gNW1)[i];
    for (int i = t; i < 1024; i += 256) ((float4*)sNW2)[i] = ((const float4*)gNW2)[i];
    if (t < 64) { sNB1[t] = gNB1[t]; sNB2[t] = gNB2[t]; }
    __syncthreads();

    const int n = blockIdx.x * 256 + t;
    if (n >= NN) return;
    const float4* hh4 = (const float4*)(hh + (size_t)n * 64);

    float a[64];

    // ---- vw path (only a[64] live) ----
    #pragma unroll
    for (int j = 0; j < 64; j++) a[j] = gVB1[j];
    #pragma unroll 1
    for (int kk = 0; kk < 16; kk++) {
        const float4 h4 = hh4[kk];
        const float av[4] = {h4.x, h4.y, h4.z, h4.w};
        #pragma unroll
        for (int u = 0; u < 4; u++) {
            const float v = av[u];
            const int k = kk * 4 + u;
            #pragma unroll
            for (int j = 0; j < 64; j++) a[j] += v * gVW1[k * 64 + j];
        }
    }
    float vw = gVB2[0];
    #pragma unroll
    for (int k = 0; k < 64; k++) vw += silu(a[k]) * gVW2[k];

    // ---- gw path (reuses a[64]) ----
    #pragma unroll
    for (int j = 0; j < 64; j++) a[j] = gGB1[j];
    #pragma unroll 1
    for (int kk = 0; kk < 16; kk++) {
        const float4 h4 = hh4[kk];
        const float av[4] = {h4.x, h4.y, h4.z, h4.w};
        #pragma unroll
        for (int u = 0; u < 4; u++) {
            const float v = av[u];
            const int k = kk * 4 + u;
            #pragma unroll
            for (int j = 0; j < 64; j++) a[j] += v * gGW1[k * 64 + j];
        }
    }
    float gw = gGB2[0];
    #pragma unroll
    for (int k = 0; k < 64; k++) gw += silu(a[k]) * gGW2[k];

    const float cn = fmaxf((float)(off[n + 1] - off[n]), 1.0f);
    #pragma unroll
    for (int d = 0; d < 3; d++)
        coord[3 * n + d] += csum[3 * n + d] / cn
                          + vw * vsrc[3 * n + d]
                          + gw * field[3 * n + d];

    // ---- node MLP: a = silu(n_in @ NW1 + b1) ----
    #pragma unroll
    for (int j = 0; j < 64; j++) a[j] = sNB1[j];
    #pragma unroll 1
    for (int kk = 0; kk < 16; kk++) {
        const float4 h4 = hh4[kk];
        const float av[4] = {h4.x, h4.y, h4.z, h4.w};
        #pragma unroll
        for (int u = 0; u < 4; u++) {
            const float v = av[u];
            const float* w = &sNW1[(kk * 4 + u) * 64];
            #pragma unroll
            for (int j = 0; j < 64; j++) a[j] += v * w[j];
        }
    }
    const float4* mg4 = (const float4*)(magg + (size_t)n * 64);
    #pragma unroll 1
    for (int kk = 0; kk < 16; kk++) {
        const float4 m4 = mg4[kk];
        const float av[4] = {m4.x, m4.y, m4.z, m4.w};
        #pragma unroll
        for (int u = 0; u < 4; u++) {
            const float v = av[u];
            const float* w = &sNW1[(64 + kk * 4 + u) * 64];
            #pragma unroll
            for (int j = 0; j < 64; j++) a[j] += v * w[j];
        }
    }
    #pragma unroll
    for (int k = 0; k < 64; k++) a[k] = silu(a[k]);

    // ---- hh_out = a @ NW2 + b2, chunked 4x16 (live: a[64] + o[16]) ----
    #pragma unroll
    for (int c4 = 0; c4 < 4; c4++) {
        float o[16];
        #pragma unroll
        for (int j = 0; j < 16; j++) o[j] = sNB2[c4 * 16 + j];
        #pragma unroll
        for (int k = 0; k < 64; k++) {
            const float v = a[k];
            const float* w = &sNW2[k * 64 + c4 * 16];
            #pragma unroll
            for (int j = 0; j < 16; j++) o[j] += v * w[j];
        }
        #pragma unroll
        for (int j = 0; j < 16; j++) hh[(size_t)n * 64 + c4 * 16 + j] = o[j];
    }
}

// ---- host launch -------------------------------------------------------------
extern "C" void kernel_launch(void* const* d_in, const int* in_sizes, int n_in,
                              void* d_out, int out_size, void* d_ws, size_t ws_size,
                              hipStream_t stream) {
    float* wsf = (float*)d_ws;
    int*   wsi = (int*)(wsf + 1340000);
    float* coord = (float*)d_out;          // fp32 coord state lives in d_out
    const int* edges = (const int*)d_in[4];
    const int* rows = edges;
    const int* cols = edges + NE;

    // ---- CSR build (once per call) ----
    hipMemsetAsync(wsi + IOFF_CNTI, 0, NN * sizeof(int), stream);
    counti_kernel<<<(NE + 255) / 256, 256, 0, stream>>>(rows, wsi + IOFF_CNTI);
    scan_kernel<<<1, 1024, 0, stream>>>(wsi + IOFF_CNTI, wsi + IOFF_OFF, wsi + IOFF_CURSOR);
    scatter_kernel<<<(NE + 255) / 256, 256, 0, stream>>>(rows, wsi + IOFF_CURSOR,
                                                         wsi + IOFF_PERM);

    node_init<<<(NN + 255) / 256, 256, 0, stream>>>(
        (const float*)d_in[0], (const float*)d_in[1], (const float*)d_in[2],
        (const int*)d_in[5], (const float*)d_in[8],
        (const float*)d_in[9],  (const float*)d_in[10],
        (const float*)d_in[11], (const float*)d_in[12],
        (const float*)d_in[13], (const float*)d_in[14],
        (const float*)d_in[6],  (const float*)d_in[7],
        coord, wsf + OFF_FIELD, wsf + OFF_HH);

    for (int l = 0; l < NL; l++) {
        hipMemsetAsync(wsf + OFF_CSUM, 0, (30000 + 640000) * sizeof(float), stream);
        edge_kernel<<<NBLK, 256, 0, stream>>>(
            rows, cols, wsi + IOFF_PERM,
            coord, wsf + OFF_HH, (const float*)d_in[3],
            ((const float*)d_in[15]) + l * 8384, ((const float*)d_in[16]) + l * 64,
            ((const float*)d_in[17]) + l * 4096, ((const float*)d_in[18]) + l * 64,
            ((const float*)d_in[23]) + l * 4096, ((const float*)d_in[24]) + l * 64,
            ((const float*)d_in[25]) + l * 64,
            wsf + OFF_CSUM, wsf + OFF_MAGG);
        node_kernel<<<(NN + 255) / 256, 256, 0, stream>>>(
            ((const float*)d_in[26]) + l * 4096, ((const float*)d_in[27]) + l * 64,
            ((const float*)d_in[28]) + l * 64,   ((const float*)d_in[29]) + l,
            ((const float*)d_in[30]) + l * 4096, ((const float*)d_in[31]) + l * 64,
            ((const float*)d_in[32]) + l * 64,   ((const float*)d_in[33]) + l,
            ((const float*)d_in[19]) + l * 8192, ((const float*)d_in[20]) + l * 64,
            ((const float*)d_in[21]) + l * 4096, ((const float*)d_in[22]) + l * 64,
            wsf + OFF_CSUM, wsi + IOFF_OFF, (const float*)d_in[2],
            wsf + OFF_FIELD, wsf + OFF_MAGG, coord, wsf + OFF_HH);
    }
}

// Round 2
// 9097.253 us; speedup vs baseline: 2.8624x; 2.8624x over previous
//
#include <hip/hip_runtime.h>
#include <hip/hip_bf16.h>

typedef unsigned short ushort_t;
typedef unsigned int uint_t;

#define NN    10000
#define NE    320000
#define NL    4
#define NBLK  1250      // NE / 256 exactly

// ---- workspace float offsets -------------------------------------------------
// coord lives directly in d_out (fp32, 30000 elems, fully initialized by node_init)
#define OFF_FIELD 0        // 30000
#define OFF_HH    30000    // 640000
#define OFF_CSUM  670000   // 30000  (contiguous with MAGG for one memset)
#define OFF_MAGG  700000   // 640000 -> float end 1340000
// ---- int region (starts at float offset 1340000) ----------------------------
#define IOFF_CNTI   0        // 10000
#define IOFF_OFF    10000    // 10001
#define IOFF_CURSOR 20001    // 10000
#define IOFF_PERM   30001    // 320000 -> int end 350001 (total ws ~6.76 MB)

__device__ __forceinline__ float silu(float x) {
    return x / (1.0f + __expf(-x));
}
// fp32 -> bf16 round-to-nearest-even
__device__ __forceinline__ ushort_t f2bf(float f) {
    union { float f; uint_t u; } v; v.f = f;
    const uint_t r = (v.u + 0x7FFFu + ((v.u >> 16) & 1u)) >> 16;
    return (ushort_t)r;
}
__device__ __forceinline__ void unpack2(uint_t p, float& lo, float& hi) {
    union { uint_t u; float f; } a, b;
    a.u = p << 16; b.u = p & 0xffff0000u;
    lo = a.f; hi = b.f;
}

// ---- CSR build: per-row int counts ------------------------------------------
__global__ __launch_bounds__(256) void counti_kernel(const int* __restrict__ rows,
                                                     int* __restrict__ cnti) {
    const int e = blockIdx.x * 256 + threadIdx.x;
    if (e < NE) {
        int r = rows[e];
        r = ((uint_t)r < (uint_t)NN) ? r : 0;
        atomicAdd(&cnti[r], 1);
    }
}

// ---- CSR build: exclusive scan over 10000 counts (single block) --------------
__global__ __launch_bounds__(1024) void scan_kernel(const int* __restrict__ cnti,
                                                    int* __restrict__ off,
                                                    int* __restrict__ cursor) {
    __shared__ int part[1024];
    const int t = threadIdx.x;
    const int base = t * 10;
    int loc[10];
    int s = 0;
    #pragma unroll
    for (int i = 0; i < 10; i++) {
        const int idx = base + i;
        const int v = (idx < NN) ? cnti[idx] : 0;
        loc[i] = s; s += v;
    }
    part[t] = s;
    __syncthreads();
    const int own = s;
    for (int d = 1; d < 1024; d <<= 1) {
        const int v = (t >= d) ? part[t - d] : 0;
        __syncthreads();
        part[t] += v;
        __syncthreads();
    }
    const int excl = part[t] - own;
    #pragma unroll
    for (int i = 0; i < 10; i++) {
        const int idx = base + i;
        if (idx < NN) { const int o = excl + loc[i]; off[idx] = o; cursor[idx] = o; }
    }
    if (t == 0) off[NN] = NE;
}

// ---- CSR build: scatter edge ids into row-sorted order -----------------------
__global__ __launch_bounds__(256) void scatter_kernel(const int* __restrict__ rows,
                                                      int* __restrict__ cursor,
                                                      int* __restrict__ perm) {
    const int e = blockIdx.x * 256 + threadIdx.x;
    if (e < NE) {
        int r = rows[e];
        r = ((uint_t)r < (uint_t)NN) ? r : 0;
        const int pos = atomicAdd(&cursor[r], 1);
        if ((uint_t)pos < (uint_t)NE) perm[pos] = e;
    }
}

// ---- field network + node embedding + coord init (once per call) ------------
__global__ __launch_bounds__(256) void node_init(
    const float* __restrict__ hsrc, const float* __restrict__ xsrc,
    const float* __restrict__ vsrc, const int* __restrict__ charges,
    const float* __restrict__ cls,
    const float* __restrict__ fW1, const float* __restrict__ fb1,
    const float* __restrict__ fW2, const float* __restrict__ fb2,
    const float* __restrict__ fW3, const float* __restrict__ fb3,
    const float* __restrict__ embW, const float* __restrict__ embb,
    float* __restrict__ coord, float* __restrict__ field, float* __restrict__ hh)
{
    __shared__ float sFW1[704], sFW2[1024], sFW3[96];
    __shared__ float sFB1[32], sFB2[32], sFB3[3], sCLS[32], sEW[64], sEB[64];
    const int t = threadIdx.x;
    for (int i = t; i < 704; i += 256) sFW1[i] = fW1[i];
    for (int i = t; i < 1024; i += 256) sFW2[i] = fW2[i];
    if (t < 96) sFW3[t] = fW3[t];
    if (t < 32) { sFB1[t] = fb1[t]; sFB2[t] = fb2[t]; sCLS[t] = cls[t]; }
    if (t < 3)  sFB3[t] = fb3[t];
    if (t < 64) { sEW[t] = embW[t]; sEB[t] = embb[t]; }
    __syncthreads();

    const int n = blockIdx.x * 256 + t;
    if (n >= NN) return;

    float fin[22];
    #pragma unroll
    for (int d = 0; d < 3; d++) {
        fin[d]     = xsrc[3 * n + d];
        fin[3 + d] = vsrc[3 * n + d];
        coord[3 * n + d] = fin[d];
    }
    int ci = charges[n];
    ci = ((uint_t)ci < 2u) ? ci : 0;
    const int cix = ci * 16;
    #pragma unroll
    for (int k = 0; k < 16; k++) fin[6 + k] = sCLS[cix + k];

    float h1[32];
    #pragma unroll
    for (int j = 0; j < 32; j++) h1[j] = sFB1[j];
    #pragma unroll
    for (int k = 0; k < 22; k++) {
        const float v = fin[k];
        #pragma unroll
        for (int j = 0; j < 32; j++) h1[j] += v * sFW1[k * 32 + j];
    }
    #pragma unroll
    for (int j = 0; j < 32; j++) h1[j] = silu(h1[j]);

    float h2[32];
    #pragma unroll
    for (int j = 0; j < 32; j++) h2[j] = sFB2[j];
    #pragma unroll
    for (int k = 0; k < 32; k++) {
        const float v = h1[k];
        #pragma unroll
        for (int j = 0; j < 32; j++) h2[j] += v * sFW2[k * 32 + j];
    }
    #pragma unroll
    for (int j = 0; j < 32; j++) h2[j] = silu(h2[j]);

    #pragma unroll
    for (int d = 0; d < 3; d++) {
        float s = sFB3[d];
        #pragma unroll
        for (int j = 0; j < 32; j++) s += h2[j] * sFW3[j * 3 + d];
        field[3 * n + d] = s;
    }

    const float hv = hsrc[n];
    #pragma unroll
    for (int j = 0; j < 64; j++) hh[(size_t)n * 64 + j] = hv * sEW[j] + sEB[j];
}

// ---- edge kernel helpers -----------------------------------------------------
// One 16-channel chunk of the edge-MLP hidden layer, folded immediately into m.
// Peak live registers inside: m[64] + acc16[16] + temps (~100) — fits without
// scratch demotion. All private indexing is compile-time (C16 is a template arg).
template<int C16>
__device__ __forceinline__ void edge_acc_chunk(
    const float4* __restrict__ hr4, const float4* __restrict__ hc4,
    const float radial, const float eax, const float eay,
    const ushort_t* sW1, const float* sW2, const float* sB1,
    float (&m)[64])
{
    float acc16[16];
    #pragma unroll
    for (int j = 0; j < 16; j++) acc16[j] = sB1[C16 * 16 + j];

    #pragma unroll 2
    for (int kk = 0; kk < 16; kk++) {
        const float4 a = hr4[kk];
        const float av[4] = {a.x, a.y, a.z, a.w};
        #pragma unroll
        for (int u = 0; u < 4; u++) {
            const float v = av[u];
            const uint_t* w = (const uint_t*)&sW1[(kk * 4 + u) * 64] + C16 * 8;
            #pragma unroll
            for (int j2 = 0; j2 < 8; j2++) {
                float lo, hi; unpack2(w[j2], lo, hi);
                acc16[2 * j2]     += v * lo;
                acc16[2 * j2 + 1] += v * hi;
            }
        }
    }
    #pragma unroll 2
    for (int kk = 0; kk < 16; kk++) {
        const float4 a = hc4[kk];
        const float av[4] = {a.x, a.y, a.z, a.w};
        #pragma unroll
        for (int u = 0; u < 4; u++) {
            const float v = av[u];
            const uint_t* w = (const uint_t*)&sW1[(64 + kk * 4 + u) * 64] + C16 * 8;
            #pragma unroll
            for (int j2 = 0; j2 < 8; j2++) {
                float lo, hi; unpack2(w[j2], lo, hi);
                acc16[2 * j2]     += v * lo;
                acc16[2 * j2 + 1] += v * hi;
            }
        }
    }
    {
        const float ext[3] = {radial, eax, eay};
        #pragma unroll
        for (int x = 0; x < 3; x++) {
            const float v = ext[x];
            const uint_t* w = (const uint_t*)&sW1[(128 + x) * 64] + C16 * 8;
            #pragma unroll
            for (int j2 = 0; j2 < 8; j2++) {
                float lo, hi; unpack2(w[j2], lo, hi);
                acc16[2 * j2]     += v * lo;
                acc16[2 * j2 + 1] += v * hi;
            }
        }
    }
    #pragma unroll
    for (int j = 0; j < 16; j++) acc16[j] = silu(acc16[j]);

    // m += acc16 @ W2[C16*16 : C16*16+16, :]   (fully unrolled: all const idx)
    #pragma unroll
    for (int k = 0; k < 16; k++) {
        const float v = acc16[k];
        const float* w2 = &sW2[(C16 * 16 + k) * 64];
        #pragma unroll
        for (int j = 0; j < 64; j++) m[j] += v * w2[j];
    }
}

// One 16-wide chunk of cw = silu(m @ cW1 + cb1) @ cW2. Live: m[64]+chv[16].
template<int C4>
__device__ __forceinline__ float edge_cw_chunk(
    const float (&m)[64], const ushort_t* sCW1, const float* sCB1,
    const float* sCW2v)
{
    float chv[16];
    #pragma unroll
    for (int j = 0; j < 16; j++) chv[j] = sCB1[C4 * 16 + j];
    #pragma unroll
    for (int k = 0; k < 64; k++) {
        const float v = m[k];
        const uint_t* w = (const uint_t*)&sCW1[k * 64] + C4 * 8;
        #pragma unroll
        for (int j2 = 0; j2 < 8; j2++) {
            float lo, hi; unpack2(w[j2], lo, hi);
            chv[2 * j2]     += v * lo;
            chv[2 * j2 + 1] += v * hi;
        }
    }
    float s = 0.f;
    #pragma unroll
    for (int j = 0; j < 16; j++) s += silu(chv[j]) * sCW2v[C4 * 16 + j];
    return s;
}

// ---- per-layer edge kernel: sorted edges + LDS segmented reduction -----------
// LDS: sW1 bf16 16768 + sW2 fp32 16384 + sCW1 bf16 8192 + biases 1024
//    + tile 16384 + srow 1024 + sscan 1024 + segstart 1028 + snseg 4 = 62832 B
__global__ __launch_bounds__(256, 2) void edge_kernel(
    const int* __restrict__ rows, const int* __restrict__ cols,
    const int* __restrict__ perm,
    const float* __restrict__ coord, const float* __restrict__ hh,
    const float* __restrict__ eattr,
    const float* __restrict__ gEW1, const float* __restrict__ gEB1,
    const float* __restrict__ gEW2, const float* __restrict__ gEB2,
    const float* __restrict__ gCW1, const float* __restrict__ gCB1,
    const float* __restrict__ gCW2,
    float* __restrict__ csum, float* __restrict__ magg)
{
    __shared__ __align__(16) ushort_t sW1[131 * 64];   // bf16
    __shared__ __align__(16) float    sW2[64 * 64];    // fp32
    __shared__ __align__(16) ushort_t sCW1[64 * 64];   // bf16
    __shared__ float sB1[64], sB2[64], sCB1[64], sCW2v[64];
    __shared__ float tile[256 * 16];
    __shared__ int   srow[256];
    __shared__ int   sscan[256];
    __shared__ int   segstart[257];
    __shared__ int   snseg;

    const int t = threadIdx.x;
    for (int i = t; i < 2096; i += 256) {          // 131*64 = 8384 = 2096 float4
        const float4 v = ((const float4*)gEW1)[i];
        sW1[4 * i + 0] = f2bf(v.x); sW1[4 * i + 1] = f2bf(v.y);
        sW1[4 * i + 2] = f2bf(v.z); sW1[4 * i + 3] = f2bf(v.w);
    }
    for (int i = t; i < 1024; i += 256) ((float4*)sW2)[i] = ((const float4*)gEW2)[i];
    for (int i = t; i < 1024; i += 256) {          // 64*64 = 4096 = 1024 float4
        const float4 v = ((const float4*)gCW1)[i];
        sCW1[4 * i + 0] = f2bf(v.x); sCW1[4 * i + 1] = f2bf(v.y);
        sCW1[4 * i + 2] = f2bf(v.z); sCW1[4 * i + 3] = f2bf(v.w);
    }
    if (t < 64) { sB1[t] = gEB1[t]; sB2[t] = gEB2[t];
                  sCB1[t] = gCB1[t]; sCW2v[t] = gCW2[t]; }

    const int ep = blockIdx.x * 256 + t;           // NE = 1250*256 exactly, no tail
    int e = perm[ep];
    e = ((uint_t)e < (uint_t)NE) ? e : 0;
    int r = rows[e], c = cols[e];
    r = ((uint_t)r < (uint_t)NN) ? r : 0;
    c = ((uint_t)c < (uint_t)NN) ? c : 0;
    srow[t] = r;
    __syncthreads();

    // block-level segment boundaries over sorted rows
    const int flag = (t == 0) ? 1 : ((srow[t] != srow[t - 1]) ? 1 : 0);
    sscan[t] = flag;
    __syncthreads();
    for (int d = 1; d < 256; d <<= 1) {
        const int v = (t >= d) ? sscan[t - d] : 0;
        __syncthreads();
        sscan[t] += v;
        __syncthreads();
    }
    const int lr = sscan[t] - 1;
    if (flag) segstart[lr] = t;
    if (t == 255) snseg = sscan[255];
    __syncthreads();
    const int nseg = snseg;
    if (t == 0) segstart[nseg] = 256;
    // (next __syncthreads before tile use covers this write)

    // ---- edge MLP, hidden layer in 16-channel chunks folded into m ----
    const float dx = coord[3 * r + 0] - coord[3 * c + 0];
    const float dy = coord[3 * r + 1] - coord[3 * c + 1];
    const float dz = coord[3 * r + 2] - coord[3 * c + 2];
    const float radial = dx * dx + dy * dy + dz * dz;
    const float2 ea = ((const float2*)eattr)[e];

    const float4* hr4 = (const float4*)(hh + (size_t)r * 64);
    const float4* hc4 = (const float4*)(hh + (size_t)c * 64);

    float m[64];
    #pragma unroll
    for (int j = 0; j < 64; j++) m[j] = sB2[j];

    edge_acc_chunk<0>(hr4, hc4, radial, ea.x, ea.y, sW1, sW2, sB1, m);
    edge_acc_chunk<1>(hr4, hc4, radial, ea.x, ea.y, sW1, sW2, sB1, m);
    edge_acc_chunk<2>(hr4, hc4, radial, ea.x, ea.y, sW1, sW2, sB1, m);
    edge_acc_chunk<3>(hr4, hc4, radial, ea.x, ea.y, sW1, sW2, sB1, m);

    #pragma unroll
    for (int j = 0; j < 64; j++) m[j] = silu(m[j]);

    // ---- cw = silu(m @ cW1 + cb1) @ cW2, 16-wide chunks ----
    float cw = 0.f;
    cw += edge_cw_chunk<0>(m, sCW1, sCB1, sCW2v);
    cw += edge_cw_chunk<1>(m, sCW1, sCB1, sCW2v);
    cw += edge_cw_chunk<2>(m, sCW1, sCB1, sCW2v);
    cw += edge_cw_chunk<3>(m, sCW1, sCB1, sCW2v);

    // ---- segmented reduction: magg, 4 chunks of 16 channels ----
    // Macro-expanded with literal CH0 so m[] stays compile-time indexed.
#define STAGE_MAGG_CHUNK(CH0)                                                   \
    __syncthreads();                                                            \
    {                                                                           \
        _Pragma("unroll")                                                       \
        for (int cc = 0; cc < 16; cc++) tile[t * 16 + cc] = m[CH0 + cc];        \
    }                                                                           \
    __syncthreads();                                                            \
    for (int w = t; w < nseg * 16; w += 256) {                                  \
        const int lr2 = w >> 4, cc = w & 15;                                    \
        const int p0 = segstart[lr2], p1 = segstart[lr2 + 1];                   \
        float s = 0.f;                                                          \
        for (int p = p0; p < p1; p++) s += tile[p * 16 + cc];                   \
        atomicAdd(&magg[(size_t)srow[p0] * 64 + CH0 + cc], s);                  \
    }

    STAGE_MAGG_CHUNK(0)
    STAGE_MAGG_CHUNK(16)
    STAGE_MAGG_CHUNK(32)
    STAGE_MAGG_CHUNK(48)
#undef STAGE_MAGG_CHUNK

    // ---- segmented reduction: csum (3 channels) ----
    __syncthreads();
    tile[t * 16 + 0] = dx * cw;
    tile[t * 16 + 1] = dy * cw;
    tile[t * 16 + 2] = dz * cw;
    __syncthreads();
    for (int w = t; w < nseg * 3; w += 256) {
        const int lr2 = w / 3, cc = w - lr2 * 3;
        const int p0 = segstart[lr2], p1 = segstart[lr2 + 1];
        float s = 0.f;
        for (int p = p0; p < p1; p++) s += tile[p * 16 + cc];
        atomicAdd(&csum[3 * srow[p0] + cc], s);
    }
}

// ---- per-layer node kernel (round-0 version, reverted verbatim) --------------
__global__ __launch_bounds__(256, 2) void node_kernel(
    const float* __restrict__ gVW1, const float* __restrict__ gVB1,
    const float* __restrict__ gVW2, const float* __restrict__ gVB2,
    const float* __restrict__ gGW1, const float* __restrict__ gGB1,
    const float* __restrict__ gGW2, const float* __restrict__ gGB2,
    const float* __restrict__ gNW1, const float* __restrict__ gNB1,
    const float* __restrict__ gNW2, const float* __restrict__ gNB2,
    const float* __restrict__ csum, const int* __restrict__ off,
    const float* __restrict__ vsrc, const float* __restrict__ field,
    const float* __restrict__ magg,
    float* __restrict__ coord, float* __restrict__ hh)
{
    __shared__ __align__(16) float sNW1[128 * 64];
    __shared__ __align__(16) float sNW2[64 * 64];
    __shared__ float sNB1[64], sNB2[64];

    const int t = threadIdx.x;
    for (int i = t; i < 2048; i += 256) ((float4*)sNW1)[i] = ((const float4*)gNW1)[i];
    for (int i = t; i < 1024; i += 256) ((float4*)sNW2)[i] = ((const float4*)gNW2)[i];
    if (t < 64) { sNB1[t] = gNB1[t]; sNB2[t] = gNB2[t]; }
    __syncthreads();

    const int n = blockIdx.x * 256 + t;
    if (n >= NN) return;
    const float4* hh4 = (const float4*)(hh + (size_t)n * 64);

    float a[64], b[64];
    #pragma unroll
    for (int j = 0; j < 64; j++) { a[j] = gVB1[j]; b[j] = gGB1[j]; }
    #pragma unroll 1
    for (int kk = 0; kk < 16; kk++) {
        const float4 h4 = hh4[kk];
        const float av[4] = {h4.x, h4.y, h4.z, h4.w};
        #pragma unroll
        for (int u = 0; u < 4; u++) {
            const float v = av[u];
            const int k = kk * 4 + u;
            #pragma unroll
            for (int j = 0; j < 64; j++) {
                a[j] += v * gVW1[k * 64 + j];
                b[j] += v * gGW1[k * 64 + j];
            }
        }
    }
    float vw = gVB2[0], gw = gGB2[0];
    #pragma unroll
    for (int k = 0; k < 64; k++) { vw += silu(a[k]) * gVW2[k]; gw += silu(b[k]) * gGW2[k]; }

    const float cn = fmaxf((float)(off[n + 1] - off[n]), 1.0f);
    #pragma unroll
    for (int d = 0; d < 3; d++)
        coord[3 * n + d] += csum[3 * n + d] / cn
                          + vw * vsrc[3 * n + d]
                          + gw * field[3 * n + d];

    #pragma unroll
    for (int j = 0; j < 64; j++) a[j] = sNB1[j];
    #pragma unroll 1
    for (int kk = 0; kk < 16; kk++) {
        const float4 h4 = hh4[kk];
        const float av[4] = {h4.x, h4.y, h4.z, h4.w};
        #pragma unroll
        for (int u = 0; u < 4; u++) {
            const float v = av[u];
            const float* w = &sNW1[(kk * 4 + u) * 64];
            #pragma unroll
            for (int j = 0; j < 64; j++) a[j] += v * w[j];
        }
    }
    const float4* mg4 = (const float4*)(magg + (size_t)n * 64);
    #pragma unroll 1
    for (int kk = 0; kk < 16; kk++) {
        const float4 m4 = mg4[kk];
        const float av[4] = {m4.x, m4.y, m4.z, m4.w};
        #pragma unroll
        for (int u = 0; u < 4; u++) {
            const float v = av[u];
            const float* w = &sNW1[(64 + kk * 4 + u) * 64];
            #pragma unroll
            for (int j = 0; j < 64; j++) a[j] += v * w[j];
        }
    }
    #pragma unroll
    for (int k = 0; k < 64; k++) a[k] = silu(a[k]);

    float o[64];
    #pragma unroll
    for (int j = 0; j < 64; j++) o[j] = sNB2[j];
    #pragma unroll 1
    for (int k = 0; k < 64; k++) {
        const float v = a[k];
        const float* w = &sNW2[k * 64];
        #pragma unroll
        for (int j = 0; j < 64; j++) o[j] += v * w[j];
    }
    #pragma unroll
    for (int j = 0; j < 64; j++) hh[(size_t)n * 64 + j] = o[j];
}

// ---- host launch -------------------------------------------------------------
extern "C" void kernel_launch(void* const* d_in, const int* in_sizes, int n_in,
                              void* d_out, int out_size, void* d_ws, size_t ws_size,
                              hipStream_t stream) {
    float* wsf = (float*)d_ws;
    int*   wsi = (int*)(wsf + 1340000);
    float* coord = (float*)d_out;          // fp32 coord state lives in d_out
    const int* edges = (const int*)d_in[4];
    const int* rows = edges;
    const int* cols = edges + NE;

    // ---- CSR build (once per call) ----
    hipMemsetAsync(wsi + IOFF_CNTI, 0, NN * sizeof(int), stream);
    counti_kernel<<<(NE + 255) / 256, 256, 0, stream>>>(rows, wsi + IOFF_CNTI);
    scan_kernel<<<1, 1024, 0, stream>>>(wsi + IOFF_CNTI, wsi + IOFF_OFF, wsi + IOFF_CURSOR);
    scatter_kernel<<<(NE + 255) / 256, 256, 0, stream>>>(rows, wsi + IOFF_CURSOR,
                                                         wsi + IOFF_PERM);

    node_init<<<(NN + 255) / 256, 256, 0, stream>>>(
        (const float*)d_in[0], (const float*)d_in[1], (const float*)d_in[2],
        (const int*)d_in[5], (const float*)d_in[8],
        (const float*)d_in[9],  (const float*)d_in[10],
        (const float*)d_in[11], (const float*)d_in[12],
        (const float*)d_in[13], (const float*)d_in[14],
        (const float*)d_in[6],  (const float*)d_in[7],
        coord, wsf + OFF_FIELD, wsf + OFF_HH);

    for (int l = 0; l < NL; l++) {
        hipMemsetAsync(wsf + OFF_CSUM, 0, (30000 + 640000) * sizeof(float), stream);
        edge_kernel<<<NBLK, 256, 0, stream>>>(
            rows, cols, wsi + IOFF_PERM,
            coord, wsf + OFF_HH, (const float*)d_in[3],
            ((const float*)d_in[15]) + l * 8384, ((const float*)d_in[16]) + l * 64,
            ((const float*)d_in[17]) + l * 4096, ((const float*)d_in[18]) + l * 64,
            ((const float*)d_in[23]) + l * 4096, ((const float*)d_in[24]) + l * 64,
            ((const float*)d_in[25]) + l * 64,
            wsf + OFF_CSUM, wsf + OFF_MAGG);
        node_kernel<<<(NN + 255) / 256, 256, 0, stream>>>(
            ((const float*)d_in[26]) + l * 4096, ((const float*)d_in[27]) + l * 64,
            ((const float*)d_in[28]) + l * 64,   ((const float*)d_in[29]) + l,
            ((const float*)d_in[30]) + l * 4096, ((const float*)d_in[31]) + l * 64,
            ((const float*)d_in[32]) + l * 64,   ((const float*)d_in[33]) + l,
            ((const float*)d_in[19]) + l * 8192, ((const float*)d_in[20]) + l * 64,
            ((const float*)d_in[21]) + l * 4096, ((const float*)d_in[22]) + l * 64,
            wsf + OFF_CSUM, wsi + IOFF_OFF, (const float*)d_in[2],
            wsf + OFF_FIELD, wsf + OFF_MAGG, coord, wsf + OFF_HH);
    }
}

// Round 3
// 2213.541 us; speedup vs baseline: 11.7640x; 4.1098x over previous
//
#include <hip/hip_runtime.h>
#include <hip/hip_bf16.h>

typedef unsigned short ushort_t;
typedef unsigned int uint_t;

#define NN    10000
#define NE    320000
#define NL    4
#define EBLK  64        // edges per block (4 threads per edge)
#define NEBLK 5000      // NE / EBLK exactly

// ---- workspace float offsets -------------------------------------------------
// coord lives directly in d_out (fp32, 30000 elems, fully initialized by node_init)
#define OFF_FIELD 0        // 30000
#define OFF_HH    30000    // 640000
#define OFF_CSUM  670000   // 30000  (contiguous with MAGG for one memset)
#define OFF_MAGG  700000   // 640000 -> float end 1340000
// ---- int region (starts at float offset 1340000) ----------------------------
#define IOFF_CNTI   0        // 10000
#define IOFF_OFF    10000    // 10001
#define IOFF_CURSOR 20001    // 10000
#define IOFF_PERM   30001    // 320000 -> int end 350001 (total ws ~6.76 MB)

__device__ __forceinline__ float silu(float x) {
    return x / (1.0f + __expf(-x));
}
// fp32 -> bf16 round-to-nearest-even
__device__ __forceinline__ ushort_t f2bf(float f) {
    union { float f; uint_t u; } v; v.f = f;
    const uint_t r = (v.u + 0x7FFFu + ((v.u >> 16) & 1u)) >> 16;
    return (ushort_t)r;
}
__device__ __forceinline__ void unpack2(uint_t p, float& lo, float& hi) {
    union { uint_t u; float f; } a, b;
    a.u = p << 16; b.u = p & 0xffff0000u;
    lo = a.f; hi = b.f;
}

// ---- CSR build: per-row int counts ------------------------------------------
__global__ __launch_bounds__(256) void counti_kernel(const int* __restrict__ rows,
                                                     int* __restrict__ cnti) {
    const int e = blockIdx.x * 256 + threadIdx.x;
    if (e < NE) {
        int r = rows[e];
        r = ((uint_t)r < (uint_t)NN) ? r : 0;
        atomicAdd(&cnti[r], 1);
    }
}

// ---- CSR build: exclusive scan over 10000 counts (single block) --------------
__global__ __launch_bounds__(1024) void scan_kernel(const int* __restrict__ cnti,
                                                    int* __restrict__ off,
                                                    int* __restrict__ cursor) {
    __shared__ int part[1024];
    const int t = threadIdx.x;
    const int base = t * 10;
    int loc[10];
    int s = 0;
    #pragma unroll
    for (int i = 0; i < 10; i++) {
        const int idx = base + i;
        const int v = (idx < NN) ? cnti[idx] : 0;
        loc[i] = s; s += v;
    }
    part[t] = s;
    __syncthreads();
    const int own = s;
    for (int d = 1; d < 1024; d <<= 1) {
        const int v = (t >= d) ? part[t - d] : 0;
        __syncthreads();
        part[t] += v;
        __syncthreads();
    }
    const int excl = part[t] - own;
    #pragma unroll
    for (int i = 0; i < 10; i++) {
        const int idx = base + i;
        if (idx < NN) { const int o = excl + loc[i]; off[idx] = o; cursor[idx] = o; }
    }
    if (t == 0) off[NN] = NE;
}

// ---- CSR build: scatter edge ids into row-sorted order -----------------------
__global__ __launch_bounds__(256) void scatter_kernel(const int* __restrict__ rows,
                                                      int* __restrict__ cursor,
                                                      int* __restrict__ perm) {
    const int e = blockIdx.x * 256 + threadIdx.x;
    if (e < NE) {
        int r = rows[e];
        r = ((uint_t)r < (uint_t)NN) ? r : 0;
        const int pos = atomicAdd(&cursor[r], 1);
        if ((uint_t)pos < (uint_t)NE) perm[pos] = e;
    }
}

// ---- field network + node embedding + coord init (once per call) ------------
__global__ __launch_bounds__(256) void node_init(
    const float* __restrict__ hsrc, const float* __restrict__ xsrc,
    const float* __restrict__ vsrc, const int* __restrict__ charges,
    const float* __restrict__ cls,
    const float* __restrict__ fW1, const float* __restrict__ fb1,
    const float* __restrict__ fW2, const float* __restrict__ fb2,
    const float* __restrict__ fW3, const float* __restrict__ fb3,
    const float* __restrict__ embW, const float* __restrict__ embb,
    float* __restrict__ coord, float* __restrict__ field, float* __restrict__ hh)
{
    __shared__ float sFW1[704], sFW2[1024], sFW3[96];
    __shared__ float sFB1[32], sFB2[32], sFB3[3], sCLS[32], sEW[64], sEB[64];
    const int t = threadIdx.x;
    for (int i = t; i < 704; i += 256) sFW1[i] = fW1[i];
    for (int i = t; i < 1024; i += 256) sFW2[i] = fW2[i];
    if (t < 96) sFW3[t] = fW3[t];
    if (t < 32) { sFB1[t] = fb1[t]; sFB2[t] = fb2[t]; sCLS[t] = cls[t]; }
    if (t < 3)  sFB3[t] = fb3[t];
    if (t < 64) { sEW[t] = embW[t]; sEB[t] = embb[t]; }
    __syncthreads();

    const int n = blockIdx.x * 256 + t;
    if (n >= NN) return;

    float fin[22];
    #pragma unroll
    for (int d = 0; d < 3; d++) {
        fin[d]     = xsrc[3 * n + d];
        fin[3 + d] = vsrc[3 * n + d];
        coord[3 * n + d] = fin[d];
    }
    int ci = charges[n];
    ci = ((uint_t)ci < 2u) ? ci : 0;
    const int cix = ci * 16;
    #pragma unroll
    for (int k = 0; k < 16; k++) fin[6 + k] = sCLS[cix + k];

    float h1[32];
    #pragma unroll
    for (int j = 0; j < 32; j++) h1[j] = sFB1[j];
    #pragma unroll
    for (int k = 0; k < 22; k++) {
        const float v = fin[k];
        #pragma unroll
        for (int j = 0; j < 32; j++) h1[j] += v * sFW1[k * 32 + j];
    }
    #pragma unroll
    for (int j = 0; j < 32; j++) h1[j] = silu(h1[j]);

    float h2[32];
    #pragma unroll
    for (int j = 0; j < 32; j++) h2[j] = sFB2[j];
    #pragma unroll
    for (int k = 0; k < 32; k++) {
        const float v = h1[k];
        #pragma unroll
        for (int j = 0; j < 32; j++) h2[j] += v * sFW2[k * 32 + j];
    }
    #pragma unroll
    for (int j = 0; j < 32; j++) h2[j] = silu(h2[j]);

    #pragma unroll
    for (int d = 0; d < 3; d++) {
        float s = sFB3[d];
        #pragma unroll
        for (int j = 0; j < 32; j++) s += h2[j] * sFW3[j * 3 + d];
        field[3 * n + d] = s;
    }

    const float hv = hsrc[n];
    #pragma unroll
    for (int j = 0; j < 64; j++) hh[(size_t)n * 64 + j] = hv * sEW[j] + sEB[j];
}

// ---- per-layer edge kernel: 4 threads per edge, 16 channels per thread -------
// Thread (ei, q): ei = t>>2 edge-in-block, q = t&3 channel chunk.
// Per-thread live set ~40 floats -> no scratch demotion possible (the structural
// fix for rounds 0-2 where a 64-wide fp32 accumulator was demoted to scratch).
// 64-wide activations are exchanged via a 16KB LDS tile with granule-XOR
// swizzle: channel ch of edge ei lives at float4-granule ei*16 + ((ch>>2)^(ei&7)),
// word ch&3. All access patterns (f4 write, per-edge f4 read, reduction b32
// read) are then bank-even.
// LDS: sW1 16768 + sW2 16384 + sCW1 8192 + biases 1024 + tile 16384
//    + sr/sc/se 768 + sscan 256 + segstart 260 + snseg 4 = 60040 B -> 2 blk/CU
__global__ __launch_bounds__(256, 2) void edge_kernel(
    const int* __restrict__ rows, const int* __restrict__ cols,
    const int* __restrict__ perm,
    const float* __restrict__ coord, const float* __restrict__ hh,
    const float* __restrict__ eattr,
    const float* __restrict__ gEW1, const float* __restrict__ gEB1,
    const float* __restrict__ gEW2, const float* __restrict__ gEB2,
    const float* __restrict__ gCW1, const float* __restrict__ gCB1,
    const float* __restrict__ gCW2,
    float* __restrict__ csum, float* __restrict__ magg)
{
    __shared__ __align__(16) ushort_t sW1[131 * 64];   // bf16 edge-MLP W1
    __shared__ __align__(16) float    sW2[64 * 64];    // fp32 edge-MLP W2
    __shared__ __align__(16) ushort_t sCW1[64 * 64];   // bf16 coord-MLP W1
    __shared__ float sB1[64], sB2[64], sCB1[64], sCW2v[64];
    __shared__ __align__(16) float tile[EBLK * 64];    // activation exchange + reduce
    __shared__ int   sr[EBLK], sc[EBLK], se[EBLK];
    __shared__ int   sscan[EBLK];
    __shared__ int   segstart[EBLK + 1];
    __shared__ int   snseg;

    const int t = threadIdx.x;
    // ---- stage weights (bf16 where proven safe in rounds 0-2) ----
    for (int i = t; i < 2096; i += 256) {          // 131*64 = 8384 = 2096 float4
        const float4 v = ((const float4*)gEW1)[i];
        sW1[4 * i + 0] = f2bf(v.x); sW1[4 * i + 1] = f2bf(v.y);
        sW1[4 * i + 2] = f2bf(v.z); sW1[4 * i + 3] = f2bf(v.w);
    }
    for (int i = t; i < 1024; i += 256) ((float4*)sW2)[i] = ((const float4*)gEW2)[i];
    for (int i = t; i < 1024; i += 256) {          // 64*64 = 4096 = 1024 float4
        const float4 v = ((const float4*)gCW1)[i];
        sCW1[4 * i + 0] = f2bf(v.x); sCW1[4 * i + 1] = f2bf(v.y);
        sCW1[4 * i + 2] = f2bf(v.z); sCW1[4 * i + 3] = f2bf(v.w);
    }
    if (t < 64) { sB1[t] = gEB1[t]; sB2[t] = gEB2[t];
                  sCB1[t] = gCB1[t]; sCW2v[t] = gCW2[t]; }

    // ---- load this block's 64 edges (sorted by row via perm) ----
    if (t < EBLK) {
        int e = perm[blockIdx.x * EBLK + t];
        e = ((uint_t)e < (uint_t)NE) ? e : 0;
        int r = rows[e], c = cols[e];
        r = ((uint_t)r < (uint_t)NN) ? r : 0;
        c = ((uint_t)c < (uint_t)NN) ? c : 0;
        se[t] = e; sr[t] = r; sc[t] = c;
    }
    __syncthreads();

    // ---- segment boundaries over the 64 sorted rows ----
    int flag = 0;
    if (t < EBLK) {
        flag = (t == 0) ? 1 : ((sr[t] != sr[t - 1]) ? 1 : 0);
        sscan[t] = flag;
    }
    __syncthreads();
    for (int d = 1; d < EBLK; d <<= 1) {
        int v = 0;
        if (t < EBLK && t >= d) v = sscan[t - d];
        __syncthreads();
        if (t < EBLK) sscan[t] += v;
        __syncthreads();
    }
    if (t < EBLK && flag) segstart[sscan[t] - 1] = t;
    if (t == EBLK - 1) snseg = sscan[EBLK - 1];
    __syncthreads();
    const int nseg = snseg;
    if (t == 0) segstart[nseg] = EBLK;
    // (covered by syncs before the reductions below)

    // ---- per-thread edge/chunk identity ----
    const int ei = t >> 2;          // edge in block
    const int q  = t & 3;           // channel chunk (16 ch)
    const int sw = ei & 7;          // tile swizzle key
    const int r = sr[ei], c = sc[ei], e = se[ei];

    const float dx = coord[3 * r + 0] - coord[3 * c + 0];
    const float dy = coord[3 * r + 1] - coord[3 * c + 1];
    const float dz = coord[3 * r + 2] - coord[3 * c + 2];
    const float radial = dx * dx + dy * dy + dz * dz;
    const float2 ea = ((const float2*)eattr)[e];

    const float4* hr4 = (const float4*)(hh + (size_t)r * 64);
    const float4* hc4 = (const float4*)(hh + (size_t)c * 64);
    const uint_t* sW1u = (const uint_t*)sW1;
    float4* tile4 = (float4*)tile;

    // ---- hidden layer: acc16 = silu(in131 @ W1[:, q*16..+16]) ----
    // k-order identical to rounds 0-2 (hh[r] 0..63, hh[c] 64..127, ext 128..130)
    float acc16[16];
    #pragma unroll
    for (int j = 0; j < 16; j++) acc16[j] = sB1[q * 16 + j];

    #pragma unroll 2
    for (int kk = 0; kk < 16; kk++) {
        const float4 a = hr4[kk];
        const float av[4] = {a.x, a.y, a.z, a.w};
        #pragma unroll
        for (int u = 0; u < 4; u++) {
            const float v = av[u];
            const uint_t* w = sW1u + (kk * 4 + u) * 32 + q * 8;
            #pragma unroll
            for (int jj = 0; jj < 8; jj++) {
                float lo, hi; unpack2(w[jj], lo, hi);
                acc16[2 * jj]     += v * lo;
                acc16[2 * jj + 1] += v * hi;
            }
        }
    }
    #pragma unroll 2
    for (int kk = 0; kk < 16; kk++) {
        const float4 a = hc4[kk];
        const float av[4] = {a.x, a.y, a.z, a.w};
        #pragma unroll
        for (int u = 0; u < 4; u++) {
            const float v = av[u];
            const uint_t* w = sW1u + (64 + kk * 4 + u) * 32 + q * 8;
            #pragma unroll
            for (int jj = 0; jj < 8; jj++) {
                float lo, hi; unpack2(w[jj], lo, hi);
                acc16[2 * jj]     += v * lo;
                acc16[2 * jj + 1] += v * hi;
            }
        }
    }
    {
        const float ext[3] = {radial, ea.x, ea.y};
        #pragma unroll
        for (int x = 0; x < 3; x++) {
            const float v = ext[x];
            const uint_t* w = sW1u + (128 + x) * 32 + q * 8;
            #pragma unroll
            for (int jj = 0; jj < 8; jj++) {
                float lo, hi; unpack2(w[jj], lo, hi);
                acc16[2 * jj]     += v * lo;
                acc16[2 * jj + 1] += v * hi;
            }
        }
    }
    #pragma unroll
    for (int j = 0; j < 16; j++) acc16[j] = silu(acc16[j]);

    // stage hidden to tile (swizzled)
    #pragma unroll
    for (int j = 0; j < 4; j++) {
        float4 v; v.x = acc16[4 * j]; v.y = acc16[4 * j + 1];
        v.z = acc16[4 * j + 2]; v.w = acc16[4 * j + 3];
        tile4[ei * 16 + ((q * 4 + j) ^ sw)] = v;
    }
    __syncthreads();

    // ---- layer 2: m16 = silu(hid64 @ W2[:, q*16..+16] + b2) ----
    float m16[16];
    #pragma unroll
    for (int j = 0; j < 16; j++) m16[j] = sB2[q * 16 + j];
    #pragma unroll 4
    for (int kk = 0; kk < 16; kk++) {
        const float4 h4 = tile4[ei * 16 + (kk ^ sw)];
        const float hv[4] = {h4.x, h4.y, h4.z, h4.w};
        #pragma unroll
        for (int u = 0; u < 4; u++) {
            const float v = hv[u];
            const float* w = &sW2[(kk * 4 + u) * 64 + q * 16];
            #pragma unroll
            for (int j = 0; j < 16; j++) m16[j] += v * w[j];
        }
    }
    #pragma unroll
    for (int j = 0; j < 16; j++) m16[j] = silu(m16[j]);

    __syncthreads();                 // everyone done reading hid
    #pragma unroll
    for (int j = 0; j < 4; j++) {
        float4 v; v.x = m16[4 * j]; v.y = m16[4 * j + 1];
        v.z = m16[4 * j + 2]; v.w = m16[4 * j + 3];
        tile4[ei * 16 + ((q * 4 + j) ^ sw)] = v;
    }
    __syncthreads();                 // tile now holds m for all edges

    // ---- cw = silu(m @ cW1 + cb1) @ cW2 (4-lane butterfly for the dot) ----
    float ch16[16];
    #pragma unroll
    for (int j = 0; j < 16; j++) ch16[j] = sCB1[q * 16 + j];
    {
        const uint_t* sCW1u = (const uint_t*)sCW1;
        #pragma unroll 4
        for (int kk = 0; kk < 16; kk++) {
            const float4 m4 = tile4[ei * 16 + (kk ^ sw)];
            const float mv[4] = {m4.x, m4.y, m4.z, m4.w};
            #pragma unroll
            for (int u = 0; u < 4; u++) {
                const float v = mv[u];
                const uint_t* w = sCW1u + (kk * 4 + u) * 32 + q * 8;
                #pragma unroll
                for (int jj = 0; jj < 8; jj++) {
                    float lo, hi; unpack2(w[jj], lo, hi);
                    ch16[2 * jj]     += v * lo;
                    ch16[2 * jj + 1] += v * hi;
                }
            }
        }
    }
    float part = 0.f;
    #pragma unroll
    for (int j = 0; j < 16; j++) part += silu(ch16[j]) * sCW2v[q * 16 + j];
    part += __shfl_xor(part, 1);
    part += __shfl_xor(part, 2);
    const float cw = part;

    // ---- segmented reduction: magg (all 64 channels from tile-m) ----
    for (int w = t; w < nseg * 64; w += 256) {
        const int lr2 = w >> 6, cc = w & 63;
        const int p0 = segstart[lr2], p1 = segstart[lr2 + 1];
        float s = 0.f;
        for (int p = p0; p < p1; p++)
            s += tile[p * 64 + ((((cc >> 2) ^ (p & 7)) << 2) | (cc & 3))];
        atomicAdd(&magg[(size_t)sr[p0] * 64 + cc], s);
    }
    __syncthreads();

    // ---- segmented reduction: csum (3 coords; stage in tile[0..255]) ----
    if (q < 3) tile[ei * 4 + q] = (q == 0 ? dx : (q == 1 ? dy : dz)) * cw;
    __syncthreads();
    for (int w = t; w < nseg * 3; w += 256) {
        const int lr2 = w / 3, cc = w - 3 * lr2;
        const int p0 = segstart[lr2], p1 = segstart[lr2 + 1];
        float s = 0.f;
        for (int p = p0; p < p1; p++) s += tile[p * 4 + cc];
        atomicAdd(&csum[3 * sr[p0] + cc], s);
    }
}

// ---- per-layer node kernel (round-0 version, passing at ~120us — untouched) --
__global__ __launch_bounds__(256, 2) void node_kernel(
    const float* __restrict__ gVW1, const float* __restrict__ gVB1,
    const float* __restrict__ gVW2, const float* __restrict__ gVB2,
    const float* __restrict__ gGW1, const float* __restrict__ gGB1,
    const float* __restrict__ gGW2, const float* __restrict__ gGB2,
    const float* __restrict__ gNW1, const float* __restrict__ gNB1,
    const float* __restrict__ gNW2, const float* __restrict__ gNB2,
    const float* __restrict__ csum, const int* __restrict__ off,
    const float* __restrict__ vsrc, const float* __restrict__ field,
    const float* __restrict__ magg,
    float* __restrict__ coord, float* __restrict__ hh)
{
    __shared__ __align__(16) float sNW1[128 * 64];
    __shared__ __align__(16) float sNW2[64 * 64];
    __shared__ float sNB1[64], sNB2[64];

    const int t = threadIdx.x;
    for (int i = t; i < 2048; i += 256) ((float4*)sNW1)[i] = ((const float4*)gNW1)[i];
    for (int i = t; i < 1024; i += 256) ((float4*)sNW2)[i] = ((const float4*)gNW2)[i];
    if (t < 64) { sNB1[t] = gNB1[t]; sNB2[t] = gNB2[t]; }
    __syncthreads();

    const int n = blockIdx.x * 256 + t;
    if (n >= NN) return;
    const float4* hh4 = (const float4*)(hh + (size_t)n * 64);

    float a[64], b[64];
    #pragma unroll
    for (int j = 0; j < 64; j++) { a[j] = gVB1[j]; b[j] = gGB1[j]; }
    #pragma unroll 1
    for (int kk = 0; kk < 16; kk++) {
        const float4 h4 = hh4[kk];
        const float av[4] = {h4.x, h4.y, h4.z, h4.w};
        #pragma unroll
        for (int u = 0; u < 4; u++) {
            const float v = av[u];
            const int k = kk * 4 + u;
            #pragma unroll
            for (int j = 0; j < 64; j++) {
                a[j] += v * gVW1[k * 64 + j];
                b[j] += v * gGW1[k * 64 + j];
            }
        }
    }
    float vw = gVB2[0], gw = gGB2[0];
    #pragma unroll
    for (int k = 0; k < 64; k++) { vw += silu(a[k]) * gVW2[k]; gw += silu(b[k]) * gGW2[k]; }

    const float cn = fmaxf((float)(off[n + 1] - off[n]), 1.0f);
    #pragma unroll
    for (int d = 0; d < 3; d++)
        coord[3 * n + d] += csum[3 * n + d] / cn
                          + vw * vsrc[3 * n + d]
                          + gw * field[3 * n + d];

    #pragma unroll
    for (int j = 0; j < 64; j++) a[j] = sNB1[j];
    #pragma unroll 1
    for (int kk = 0; kk < 16; kk++) {
        const float4 h4 = hh4[kk];
        const float av[4] = {h4.x, h4.y, h4.z, h4.w};
        #pragma unroll
        for (int u = 0; u < 4; u++) {
            const float v = av[u];
            const float* w = &sNW1[(kk * 4 + u) * 64];
            #pragma unroll
            for (int j = 0; j < 64; j++) a[j] += v * w[j];
        }
    }
    const float4* mg4 = (const float4*)(magg + (size_t)n * 64);
    #pragma unroll 1
    for (int kk = 0; kk < 16; kk++) {
        const float4 m4 = mg4[kk];
        const float av[4] = {m4.x, m4.y, m4.z, m4.w};
        #pragma unroll
        for (int u = 0; u < 4; u++) {
            const float v = av[u];
            const float* w = &sNW1[(64 + kk * 4 + u) * 64];
            #pragma unroll
            for (int j = 0; j < 64; j++) a[j] += v * w[j];
        }
    }
    #pragma unroll
    for (int k = 0; k < 64; k++) a[k] = silu(a[k]);

    float o[64];
    #pragma unroll
    for (int j = 0; j < 64; j++) o[j] = sNB2[j];
    #pragma unroll 1
    for (int k = 0; k < 64; k++) {
        const float v = a[k];
        const float* w = &sNW2[k * 64];
        #pragma unroll
        for (int j = 0; j < 64; j++) o[j] += v * w[j];
    }
    #pragma unroll
    for (int j = 0; j < 64; j++) hh[(size_t)n * 64 + j] = o[j];
}

// ---- host launch -------------------------------------------------------------
extern "C" void kernel_launch(void* const* d_in, const int* in_sizes, int n_in,
                              void* d_out, int out_size, void* d_ws, size_t ws_size,
                              hipStream_t stream) {
    float* wsf = (float*)d_ws;
    int*   wsi = (int*)(wsf + 1340000);
    float* coord = (float*)d_out;          // fp32 coord state lives in d_out
    const int* edges = (const int*)d_in[4];
    const int* rows = edges;
    const int* cols = edges + NE;

    // ---- CSR build (once per call) ----
    hipMemsetAsync(wsi + IOFF_CNTI, 0, NN * sizeof(int), stream);
    counti_kernel<<<(NE + 255) / 256, 256, 0, stream>>>(rows, wsi + IOFF_CNTI);
    scan_kernel<<<1, 1024, 0, stream>>>(wsi + IOFF_CNTI, wsi + IOFF_OFF, wsi + IOFF_CURSOR);
    scatter_kernel<<<(NE + 255) / 256, 256, 0, stream>>>(rows, wsi + IOFF_CURSOR,
                                                         wsi + IOFF_PERM);

    node_init<<<(NN + 255) / 256, 256, 0, stream>>>(
        (const float*)d_in[0], (const float*)d_in[1], (const float*)d_in[2],
        (const int*)d_in[5], (const float*)d_in[8],
        (const float*)d_in[9],  (const float*)d_in[10],
        (const float*)d_in[11], (const float*)d_in[12],
        (const float*)d_in[13], (const float*)d_in[14],
        (const float*)d_in[6],  (const float*)d_in[7],
        coord, wsf + OFF_FIELD, wsf + OFF_HH);

    for (int l = 0; l < NL; l++) {
        hipMemsetAsync(wsf + OFF_CSUM, 0, (30000 + 640000) * sizeof(float), stream);
        edge_kernel<<<NEBLK, 256, 0, stream>>>(
            rows, cols, wsi + IOFF_PERM,
            coord, wsf + OFF_HH, (const float*)d_in[3],
            ((const float*)d_in[15]) + l * 8384, ((const float*)d_in[16]) + l * 64,
            ((const float*)d_in[17]) + l * 4096, ((const float*)d_in[18]) + l * 64,
            ((const float*)d_in[23]) + l * 4096, ((const float*)d_in[24]) + l * 64,
            ((const float*)d_in[25]) + l * 64,
            wsf + OFF_CSUM, wsf + OFF_MAGG);
        node_kernel<<<(NN + 255) / 256, 256, 0, stream>>>(
            ((const float*)d_in[26]) + l * 4096, ((const float*)d_in[27]) + l * 64,
            ((const float*)d_in[28]) + l * 64,   ((const float*)d_in[29]) + l,
            ((const float*)d_in[30]) + l * 4096, ((const float*)d_in[31]) + l * 64,
            ((const float*)d_in[32]) + l * 64,   ((const float*)d_in[33]) + l,
            ((const float*)d_in[19]) + l * 8192, ((const float*)d_in[20]) + l * 64,
            ((const float*)d_in[21]) + l * 4096, ((const float*)d_in[22]) + l * 64,
            wsf + OFF_CSUM, wsi + IOFF_OFF, (const float*)d_in[2],
            wsf + OFF_FIELD, wsf + OFF_MAGG, coord, wsf + OFF_HH);
    }
}

// Round 4
// 1615.774 us; speedup vs baseline: 16.1162x; 1.3700x over previous
//
#include <hip/hip_runtime.h>
#include <hip/hip_bf16.h>

typedef unsigned short ushort_t;
typedef unsigned int uint_t;

#define NN    10000
#define NE    320000
#define NL    4
#define EBLK  64        // edges per block (4 threads per edge)
#define NEBLK 5000      // NE / EBLK exactly
#define NPB   64        // nodes per block in node_kernel (4 threads per node)
#define NNODEBLK 157    // ceil(NN / NPB)

// ---- workspace float offsets -------------------------------------------------
// coord lives directly in d_out (fp32, 30000 elems, fully initialized by node_init)
#define OFF_FIELD 0        // 30000
#define OFF_HH    30000    // 640000
#define OFF_CSUM  670000   // 30000  (contiguous with MAGG for one memset)
#define OFF_MAGG  700000   // 640000 -> float end 1340000
// ---- int region (starts at float offset 1340000) ----------------------------
#define IOFF_CNTI   0        // 10000
#define IOFF_OFF    10000    // 10001
#define IOFF_CURSOR 20001    // 10000
#define IOFF_PERM   30001    // 320000 -> int end 350001 (total ws ~6.76 MB)

// fast silu: v_rcp_f32 instead of IEEE divide (~1e-7 rel err, VALU-bound paths)
__device__ __forceinline__ float silu(float x) {
    return x * __builtin_amdgcn_rcpf(1.0f + __expf(-x));
}
// fp32 -> bf16 round-to-nearest-even
__device__ __forceinline__ ushort_t f2bf(float f) {
    union { float f; uint_t u; } v; v.f = f;
    const uint_t r = (v.u + 0x7FFFu + ((v.u >> 16) & 1u)) >> 16;
    return (ushort_t)r;
}
__device__ __forceinline__ void unpack2(uint_t p, float& lo, float& hi) {
    union { uint_t u; float f; } a, b;
    a.u = p << 16; b.u = p & 0xffff0000u;
    lo = a.f; hi = b.f;
}

// ---- CSR build: per-row int counts ------------------------------------------
__global__ __launch_bounds__(256) void counti_kernel(const int* __restrict__ rows,
                                                     int* __restrict__ cnti) {
    const int e = blockIdx.x * 256 + threadIdx.x;
    if (e < NE) {
        int r = rows[e];
        r = ((uint_t)r < (uint_t)NN) ? r : 0;
        atomicAdd(&cnti[r], 1);
    }
}

// ---- CSR build: exclusive scan over 10000 counts (single block) --------------
__global__ __launch_bounds__(1024) void scan_kernel(const int* __restrict__ cnti,
                                                    int* __restrict__ off,
                                                    int* __restrict__ cursor) {
    __shared__ int part[1024];
    const int t = threadIdx.x;
    const int base = t * 10;
    int loc[10];
    int s = 0;
    #pragma unroll
    for (int i = 0; i < 10; i++) {
        const int idx = base + i;
        const int v = (idx < NN) ? cnti[idx] : 0;
        loc[i] = s; s += v;
    }
    part[t] = s;
    __syncthreads();
    const int own = s;
    for (int d = 1; d < 1024; d <<= 1) {
        const int v = (t >= d) ? part[t - d] : 0;
        __syncthreads();
        part[t] += v;
        __syncthreads();
    }
    const int excl = part[t] - own;
    #pragma unroll
    for (int i = 0; i < 10; i++) {
        const int idx = base + i;
        if (idx < NN) { const int o = excl + loc[i]; off[idx] = o; cursor[idx] = o; }
    }
    if (t == 0) off[NN] = NE;
}

// ---- CSR build: scatter edge ids into row-sorted order -----------------------
__global__ __launch_bounds__(256) void scatter_kernel(const int* __restrict__ rows,
                                                      int* __restrict__ cursor,
                                                      int* __restrict__ perm) {
    const int e = blockIdx.x * 256 + threadIdx.x;
    if (e < NE) {
        int r = rows[e];
        r = ((uint_t)r < (uint_t)NN) ? r : 0;
        const int pos = atomicAdd(&cursor[r], 1);
        if ((uint_t)pos < (uint_t)NE) perm[pos] = e;
    }
}

// ---- field network + node embedding + coord init (once per call) ------------
__global__ __launch_bounds__(256) void node_init(
    const float* __restrict__ hsrc, const float* __restrict__ xsrc,
    const float* __restrict__ vsrc, const int* __restrict__ charges,
    const float* __restrict__ cls,
    const float* __restrict__ fW1, const float* __restrict__ fb1,
    const float* __restrict__ fW2, const float* __restrict__ fb2,
    const float* __restrict__ fW3, const float* __restrict__ fb3,
    const float* __restrict__ embW, const float* __restrict__ embb,
    float* __restrict__ coord, float* __restrict__ field, float* __restrict__ hh)
{
    __shared__ float sFW1[704], sFW2[1024], sFW3[96];
    __shared__ float sFB1[32], sFB2[32], sFB3[3], sCLS[32], sEW[64], sEB[64];
    const int t = threadIdx.x;
    for (int i = t; i < 704; i += 256) sFW1[i] = fW1[i];
    for (int i = t; i < 1024; i += 256) sFW2[i] = fW2[i];
    if (t < 96) sFW3[t] = fW3[t];
    if (t < 32) { sFB1[t] = fb1[t]; sFB2[t] = fb2[t]; sCLS[t] = cls[t]; }
    if (t < 3)  sFB3[t] = fb3[t];
    if (t < 64) { sEW[t] = embW[t]; sEB[t] = embb[t]; }
    __syncthreads();

    const int n = blockIdx.x * 256 + t;
    if (n >= NN) return;

    float fin[22];
    #pragma unroll
    for (int d = 0; d < 3; d++) {
        fin[d]     = xsrc[3 * n + d];
        fin[3 + d] = vsrc[3 * n + d];
        coord[3 * n + d] = fin[d];
    }
    int ci = charges[n];
    ci = ((uint_t)ci < 2u) ? ci : 0;
    const int cix = ci * 16;
    #pragma unroll
    for (int k = 0; k < 16; k++) fin[6 + k] = sCLS[cix + k];

    float h1[32];
    #pragma unroll
    for (int j = 0; j < 32; j++) h1[j] = sFB1[j];
    #pragma unroll
    for (int k = 0; k < 22; k++) {
        const float v = fin[k];
        #pragma unroll
        for (int j = 0; j < 32; j++) h1[j] += v * sFW1[k * 32 + j];
    }
    #pragma unroll
    for (int j = 0; j < 32; j++) h1[j] = silu(h1[j]);

    float h2[32];
    #pragma unroll
    for (int j = 0; j < 32; j++) h2[j] = sFB2[j];
    #pragma unroll
    for (int k = 0; k < 32; k++) {
        const float v = h1[k];
        #pragma unroll
        for (int j = 0; j < 32; j++) h2[j] += v * sFW2[k * 32 + j];
    }
    #pragma unroll
    for (int j = 0; j < 32; j++) h2[j] = silu(h2[j]);

    #pragma unroll
    for (int d = 0; d < 3; d++) {
        float s = sFB3[d];
        #pragma unroll
        for (int j = 0; j < 32; j++) s += h2[j] * sFW3[j * 3 + d];
        field[3 * n + d] = s;
    }

    const float hv = hsrc[n];
    #pragma unroll
    for (int j = 0; j < 64; j++) hh[(size_t)n * 64 + j] = hv * sEW[j] + sEB[j];
}

// ---- per-layer edge kernel: 4 threads per edge, 16 channels per thread -------
// (structure unchanged from round 3 — passed at 365us, VGPR 88, no scratch;
//  only silu got cheaper this round)
__global__ __launch_bounds__(256, 2) void edge_kernel(
    const int* __restrict__ rows, const int* __restrict__ cols,
    const int* __restrict__ perm,
    const float* __restrict__ coord, const float* __restrict__ hh,
    const float* __restrict__ eattr,
    const float* __restrict__ gEW1, const float* __restrict__ gEB1,
    const float* __restrict__ gEW2, const float* __restrict__ gEB2,
    const float* __restrict__ gCW1, const float* __restrict__ gCB1,
    const float* __restrict__ gCW2,
    float* __restrict__ csum, float* __restrict__ magg)
{
    __shared__ __align__(16) ushort_t sW1[131 * 64];   // bf16 edge-MLP W1
    __shared__ __align__(16) float    sW2[64 * 64];    // fp32 edge-MLP W2
    __shared__ __align__(16) ushort_t sCW1[64 * 64];   // bf16 coord-MLP W1
    __shared__ float sB1[64], sB2[64], sCB1[64], sCW2v[64];
    __shared__ __align__(16) float tile[EBLK * 64];    // activation exchange + reduce
    __shared__ int   sr[EBLK], sc[EBLK], se[EBLK];
    __shared__ int   sscan[EBLK];
    __shared__ int   segstart[EBLK + 1];
    __shared__ int   snseg;

    const int t = threadIdx.x;
    // ---- stage weights ----
    for (int i = t; i < 2096; i += 256) {          // 131*64 = 8384 = 2096 float4
        const float4 v = ((const float4*)gEW1)[i];
        sW1[4 * i + 0] = f2bf(v.x); sW1[4 * i + 1] = f2bf(v.y);
        sW1[4 * i + 2] = f2bf(v.z); sW1[4 * i + 3] = f2bf(v.w);
    }
    for (int i = t; i < 1024; i += 256) ((float4*)sW2)[i] = ((const float4*)gEW2)[i];
    for (int i = t; i < 1024; i += 256) {          // 64*64 = 4096 = 1024 float4
        const float4 v = ((const float4*)gCW1)[i];
        sCW1[4 * i + 0] = f2bf(v.x); sCW1[4 * i + 1] = f2bf(v.y);
        sCW1[4 * i + 2] = f2bf(v.z); sCW1[4 * i + 3] = f2bf(v.w);
    }
    if (t < 64) { sB1[t] = gEB1[t]; sB2[t] = gEB2[t];
                  sCB1[t] = gCB1[t]; sCW2v[t] = gCW2[t]; }

    // ---- load this block's 64 edges (sorted by row via perm) ----
    if (t < EBLK) {
        int e = perm[blockIdx.x * EBLK + t];
        e = ((uint_t)e < (uint_t)NE) ? e : 0;
        int r = rows[e], c = cols[e];
        r = ((uint_t)r < (uint_t)NN) ? r : 0;
        c = ((uint_t)c < (uint_t)NN) ? c : 0;
        se[t] = e; sr[t] = r; sc[t] = c;
    }
    __syncthreads();

    // ---- segment boundaries over the 64 sorted rows ----
    int flag = 0;
    if (t < EBLK) {
        flag = (t == 0) ? 1 : ((sr[t] != sr[t - 1]) ? 1 : 0);
        sscan[t] = flag;
    }
    __syncthreads();
    for (int d = 1; d < EBLK; d <<= 1) {
        int v = 0;
        if (t < EBLK && t >= d) v = sscan[t - d];
        __syncthreads();
        if (t < EBLK) sscan[t] += v;
        __syncthreads();
    }
    if (t < EBLK && flag) segstart[sscan[t] - 1] = t;
    if (t == EBLK - 1) snseg = sscan[EBLK - 1];
    __syncthreads();
    const int nseg = snseg;
    if (t == 0) segstart[nseg] = EBLK;
    // (covered by syncs before the reductions below)

    // ---- per-thread edge/chunk identity ----
    const int ei = t >> 2;          // edge in block
    const int q  = t & 3;           // channel chunk (16 ch)
    const int sw = ei & 7;          // tile swizzle key
    const int r = sr[ei], c = sc[ei], e = se[ei];

    const float dx = coord[3 * r + 0] - coord[3 * c + 0];
    const float dy = coord[3 * r + 1] - coord[3 * c + 1];
    const float dz = coord[3 * r + 2] - coord[3 * c + 2];
    const float radial = dx * dx + dy * dy + dz * dz;
    const float2 ea = ((const float2*)eattr)[e];

    const float4* hr4 = (const float4*)(hh + (size_t)r * 64);
    const float4* hc4 = (const float4*)(hh + (size_t)c * 64);
    const uint_t* sW1u = (const uint_t*)sW1;
    float4* tile4 = (float4*)tile;

    // ---- hidden layer: acc16 = silu(in131 @ W1[:, q*16..+16]) ----
    float acc16[16];
    #pragma unroll
    for (int j = 0; j < 16; j++) acc16[j] = sB1[q * 16 + j];

    #pragma unroll 2
    for (int kk = 0; kk < 16; kk++) {
        const float4 a = hr4[kk];
        const float av[4] = {a.x, a.y, a.z, a.w};
        #pragma unroll
        for (int u = 0; u < 4; u++) {
            const float v = av[u];
            const uint_t* w = sW1u + (kk * 4 + u) * 32 + q * 8;
            #pragma unroll
            for (int jj = 0; jj < 8; jj++) {
                float lo, hi; unpack2(w[jj], lo, hi);
                acc16[2 * jj]     += v * lo;
                acc16[2 * jj + 1] += v * hi;
            }
        }
    }
    #pragma unroll 2
    for (int kk = 0; kk < 16; kk++) {
        const float4 a = hc4[kk];
        const float av[4] = {a.x, a.y, a.z, a.w};
        #pragma unroll
        for (int u = 0; u < 4; u++) {
            const float v = av[u];
            const uint_t* w = sW1u + (64 + kk * 4 + u) * 32 + q * 8;
            #pragma unroll
            for (int jj = 0; jj < 8; jj++) {
                float lo, hi; unpack2(w[jj], lo, hi);
                acc16[2 * jj]     += v * lo;
                acc16[2 * jj + 1] += v * hi;
            }
        }
    }
    {
        const float ext[3] = {radial, ea.x, ea.y};
        #pragma unroll
        for (int x = 0; x < 3; x++) {
            const float v = ext[x];
            const uint_t* w = sW1u + (128 + x) * 32 + q * 8;
            #pragma unroll
            for (int jj = 0; jj < 8; jj++) {
                float lo, hi; unpack2(w[jj], lo, hi);
                acc16[2 * jj]     += v * lo;
                acc16[2 * jj + 1] += v * hi;
            }
        }
    }
    #pragma unroll
    for (int j = 0; j < 16; j++) acc16[j] = silu(acc16[j]);

    // stage hidden to tile (swizzled)
    #pragma unroll
    for (int j = 0; j < 4; j++) {
        float4 v; v.x = acc16[4 * j]; v.y = acc16[4 * j + 1];
        v.z = acc16[4 * j + 2]; v.w = acc16[4 * j + 3];
        tile4[ei * 16 + ((q * 4 + j) ^ sw)] = v;
    }
    __syncthreads();

    // ---- layer 2: m16 = silu(hid64 @ W2[:, q*16..+16] + b2) ----
    float m16[16];
    #pragma unroll
    for (int j = 0; j < 16; j++) m16[j] = sB2[q * 16 + j];
    #pragma unroll 4
    for (int kk = 0; kk < 16; kk++) {
        const float4 h4 = tile4[ei * 16 + (kk ^ sw)];
        const float hv[4] = {h4.x, h4.y, h4.z, h4.w};
        #pragma unroll
        for (int u = 0; u < 4; u++) {
            const float v = hv[u];
            const float* w = &sW2[(kk * 4 + u) * 64 + q * 16];
            #pragma unroll
            for (int j = 0; j < 16; j++) m16[j] += v * w[j];
        }
    }
    #pragma unroll
    for (int j = 0; j < 16; j++) m16[j] = silu(m16[j]);

    __syncthreads();                 // everyone done reading hid
    #pragma unroll
    for (int j = 0; j < 4; j++) {
        float4 v; v.x = m16[4 * j]; v.y = m16[4 * j + 1];
        v.z = m16[4 * j + 2]; v.w = m16[4 * j + 3];
        tile4[ei * 16 + ((q * 4 + j) ^ sw)] = v;
    }
    __syncthreads();                 // tile now holds m for all edges

    // ---- cw = silu(m @ cW1 + cb1) @ cW2 (4-lane butterfly for the dot) ----
    float ch16[16];
    #pragma unroll
    for (int j = 0; j < 16; j++) ch16[j] = sCB1[q * 16 + j];
    {
        const uint_t* sCW1u = (const uint_t*)sCW1;
        #pragma unroll 4
        for (int kk = 0; kk < 16; kk++) {
            const float4 m4 = tile4[ei * 16 + (kk ^ sw)];
            const float mv[4] = {m4.x, m4.y, m4.z, m4.w};
            #pragma unroll
            for (int u = 0; u < 4; u++) {
                const float v = mv[u];
                const uint_t* w = sCW1u + (kk * 4 + u) * 32 + q * 8;
                #pragma unroll
                for (int jj = 0; jj < 8; jj++) {
                    float lo, hi; unpack2(w[jj], lo, hi);
                    ch16[2 * jj]     += v * lo;
                    ch16[2 * jj + 1] += v * hi;
                }
            }
        }
    }
    float part = 0.f;
    #pragma unroll
    for (int j = 0; j < 16; j++) part += silu(ch16[j]) * sCW2v[q * 16 + j];
    part += __shfl_xor(part, 1);
    part += __shfl_xor(part, 2);
    const float cw = part;

    // ---- segmented reduction: magg (all 64 channels from tile-m) ----
    for (int w = t; w < nseg * 64; w += 256) {
        const int lr2 = w >> 6, cc = w & 63;
        const int p0 = segstart[lr2], p1 = segstart[lr2 + 1];
        float s = 0.f;
        for (int p = p0; p < p1; p++)
            s += tile[p * 64 + ((((cc >> 2) ^ (p & 7)) << 2) | (cc & 3))];
        atomicAdd(&magg[(size_t)sr[p0] * 64 + cc], s);
    }
    __syncthreads();

    // ---- segmented reduction: csum (3 coords; stage in tile[0..255]) ----
    if (q < 3) tile[ei * 4 + q] = (q == 0 ? dx : (q == 1 ? dy : dz)) * cw;
    __syncthreads();
    for (int w = t; w < nseg * 3; w += 256) {
        const int lr2 = w / 3, cc = w - 3 * lr2;
        const int p0 = segstart[lr2], p1 = segstart[lr2 + 1];
        float s = 0.f;
        for (int p = p0; p < p1; p++) s += tile[p * 4 + cc];
        atomicAdd(&csum[3 * sr[p0] + cc], s);
    }
}

// ---- per-layer node kernel: 4 threads per node, 16 channels per thread -------
// Same structural fix as edge_kernel: per-thread live set ~30 floats (the old
// a[64]+b[64]=128-float version was scratch-demoted, VGPR=96, ~125us/dispatch).
// vw/gw scalar dots finish with a 4-lane shfl_xor butterfly; node-MLP hidden
// is exchanged via granule-XOR-swizzled LDS tile. NW1 in LDS; vw/gw/NW2
// weights read from global (4 broadcast streams per wave, L2-resident).
// LDS: sNW1 32768 + tile 16384 + biases 512 = 49.7 KB.
__global__ __launch_bounds__(256, 2) void node_kernel(
    const float* __restrict__ gVW1, const float* __restrict__ gVB1,
    const float* __restrict__ gVW2, const float* __restrict__ gVB2,
    const float* __restrict__ gGW1, const float* __restrict__ gGB1,
    const float* __restrict__ gGW2, const float* __restrict__ gGB2,
    const float* __restrict__ gNW1, const float* __restrict__ gNB1,
    const float* __restrict__ gNW2, const float* __restrict__ gNB2,
    const float* __restrict__ csum, const int* __restrict__ off,
    const float* __restrict__ vsrc, const float* __restrict__ field,
    const float* __restrict__ magg,
    float* __restrict__ coord, float* __restrict__ hh)
{
    __shared__ __align__(16) float sNW1[128 * 64];     // 32 KB
    __shared__ __align__(16) float tile[NPB * 64];     // 16 KB exchange
    __shared__ float sNB1[64], sNB2[64];

    const int t = threadIdx.x;
    for (int i = t; i < 2048; i += 256) ((float4*)sNW1)[i] = ((const float4*)gNW1)[i];
    if (t < 64) { sNB1[t] = gNB1[t]; sNB2[t] = gNB2[t]; }
    __syncthreads();

    const int ni = t >> 2;          // node in block
    const int q  = t & 3;           // channel chunk
    const int sw = ni & 7;          // tile swizzle key
    int n = blockIdx.x * NPB + ni;
    const bool valid = (n < NN);
    n = valid ? n : (NN - 1);       // clamp for safe reads; writes predicated

    const float4* hh4 = (const float4*)(hh + (size_t)n * 64);
    const float4* mg4 = (const float4*)(magg + (size_t)n * 64);
    float4* tile4 = (float4*)tile;

    // ---- vw = silu(hh @ vW1 + vb1) @ vW2 + vb2 ----
    float a16[16];
    #pragma unroll
    for (int j = 0; j < 16; j++) a16[j] = gVB1[q * 16 + j];
    #pragma unroll 2
    for (int kk = 0; kk < 16; kk++) {
        const float4 h4 = hh4[kk];
        const float hv[4] = {h4.x, h4.y, h4.z, h4.w};
        #pragma unroll
        for (int u = 0; u < 4; u++) {
            const float v = hv[u];
            const float4* w4 = (const float4*)(gVW1 + (kk * 4 + u) * 64 + q * 16);
            #pragma unroll
            for (int j4 = 0; j4 < 4; j4++) {
                const float4 w = w4[j4];
                a16[4 * j4 + 0] += v * w.x; a16[4 * j4 + 1] += v * w.y;
                a16[4 * j4 + 2] += v * w.z; a16[4 * j4 + 3] += v * w.w;
            }
        }
    }
    float part = 0.f;
    #pragma unroll
    for (int j = 0; j < 16; j++) part += silu(a16[j]) * gVW2[q * 16 + j];
    part += __shfl_xor(part, 1);
    part += __shfl_xor(part, 2);
    const float vw = part + gVB2[0];

    // ---- gw = silu(hh @ gW1 + gb1) @ gW2 + gb2 (reuses a16) ----
    #pragma unroll
    for (int j = 0; j < 16; j++) a16[j] = gGB1[q * 16 + j];
    #pragma unroll 2
    for (int kk = 0; kk < 16; kk++) {
        const float4 h4 = hh4[kk];
        const float hv[4] = {h4.x, h4.y, h4.z, h4.w};
        #pragma unroll
        for (int u = 0; u < 4; u++) {
            const float v = hv[u];
            const float4* w4 = (const float4*)(gGW1 + (kk * 4 + u) * 64 + q * 16);
            #pragma unroll
            for (int j4 = 0; j4 < 4; j4++) {
                const float4 w = w4[j4];
                a16[4 * j4 + 0] += v * w.x; a16[4 * j4 + 1] += v * w.y;
                a16[4 * j4 + 2] += v * w.z; a16[4 * j4 + 3] += v * w.w;
            }
        }
    }
    part = 0.f;
    #pragma unroll
    for (int j = 0; j < 16; j++) part += silu(a16[j]) * gGW2[q * 16 + j];
    part += __shfl_xor(part, 1);
    part += __shfl_xor(part, 2);
    const float gw = part + gGB2[0];

    // ---- coord update (one thread per node) ----
    if (valid && q == 0) {
        const float cn = fmaxf((float)(off[n + 1] - off[n]), 1.0f);
        #pragma unroll
        for (int d = 0; d < 3; d++)
            coord[3 * n + d] += csum[3 * n + d] / cn
                              + vw * vsrc[3 * n + d]
                              + gw * field[3 * n + d];
    }

    // ---- node MLP hidden: a16 = silu([hh, magg] @ NW1[:, q*16..+16] + b1) ----
    #pragma unroll
    for (int j = 0; j < 16; j++) a16[j] = sNB1[q * 16 + j];
    #pragma unroll 2
    for (int kk = 0; kk < 16; kk++) {
        const float4 h4 = hh4[kk];
        const float hv[4] = {h4.x, h4.y, h4.z, h4.w};
        #pragma unroll
        for (int u = 0; u < 4; u++) {
            const float v = hv[u];
            const float* w = &sNW1[(kk * 4 + u) * 64 + q * 16];
            #pragma unroll
            for (int j = 0; j < 16; j++) a16[j] += v * w[j];
        }
    }
    #pragma unroll 2
    for (int kk = 0; kk < 16; kk++) {
        const float4 m4 = mg4[kk];
        const float mv[4] = {m4.x, m4.y, m4.z, m4.w};
        #pragma unroll
        for (int u = 0; u < 4; u++) {
            const float v = mv[u];
            const float* w = &sNW1[(64 + kk * 4 + u) * 64 + q * 16];
            #pragma unroll
            for (int j = 0; j < 16; j++) a16[j] += v * w[j];
        }
    }
    #pragma unroll
    for (int j = 0; j < 16; j++) a16[j] = silu(a16[j]);

    // ---- exchange hidden through swizzled tile ----
    #pragma unroll
    for (int j = 0; j < 4; j++) {
        float4 v; v.x = a16[4 * j]; v.y = a16[4 * j + 1];
        v.z = a16[4 * j + 2]; v.w = a16[4 * j + 3];
        tile4[ni * 16 + ((q * 4 + j) ^ sw)] = v;
    }
    __syncthreads();

    // ---- output: o16 = hid64 @ NW2[:, q*16..+16] + b2 ----
    float o16[16];
    #pragma unroll
    for (int j = 0; j < 16; j++) o16[j] = sNB2[q * 16 + j];
    #pragma unroll 2
    for (int kk = 0; kk < 16; kk++) {
        const float4 h4 = tile4[ni * 16 + (kk ^ sw)];
        const float hv[4] = {h4.x, h4.y, h4.z, h4.w};
        #pragma unroll
        for (int u = 0; u < 4; u++) {
            const float v = hv[u];
            const float4* w4 = (const float4*)(gNW2 + (kk * 4 + u) * 64 + q * 16);
            #pragma unroll
            for (int j4 = 0; j4 < 4; j4++) {
                const float4 w = w4[j4];
                o16[4 * j4 + 0] += v * w.x; o16[4 * j4 + 1] += v * w.y;
                o16[4 * j4 + 2] += v * w.z; o16[4 * j4 + 3] += v * w.w;
            }
        }
    }
    if (valid) {
        float4* out4 = (float4*)(hh + (size_t)n * 64 + q * 16);
        #pragma unroll
        for (int j4 = 0; j4 < 4; j4++) {
            float4 v; v.x = o16[4 * j4]; v.y = o16[4 * j4 + 1];
            v.z = o16[4 * j4 + 2]; v.w = o16[4 * j4 + 3];
            out4[j4] = v;
        }
    }
}

// ---- host launch -------------------------------------------------------------
extern "C" void kernel_launch(void* const* d_in, const int* in_sizes, int n_in,
                              void* d_out, int out_size, void* d_ws, size_t ws_size,
                              hipStream_t stream) {
    float* wsf = (float*)d_ws;
    int*   wsi = (int*)(wsf + 1340000);
    float* coord = (float*)d_out;          // fp32 coord state lives in d_out
    const int* edges = (const int*)d_in[4];
    const int* rows = edges;
    const int* cols = edges + NE;

    // ---- CSR build (once per call) ----
    hipMemsetAsync(wsi + IOFF_CNTI, 0, NN * sizeof(int), stream);
    counti_kernel<<<(NE + 255) / 256, 256, 0, stream>>>(rows, wsi + IOFF_CNTI);
    scan_kernel<<<1, 1024, 0, stream>>>(wsi + IOFF_CNTI, wsi + IOFF_OFF, wsi + IOFF_CURSOR);
    scatter_kernel<<<(NE + 255) / 256, 256, 0, stream>>>(rows, wsi + IOFF_CURSOR,
                                                         wsi + IOFF_PERM);

    node_init<<<(NN + 255) / 256, 256, 0, stream>>>(
        (const float*)d_in[0], (const float*)d_in[1], (const float*)d_in[2],
        (const int*)d_in[5], (const float*)d_in[8],
        (const float*)d_in[9],  (const float*)d_in[10],
        (const float*)d_in[11], (const float*)d_in[12],
        (const float*)d_in[13], (const float*)d_in[14],
        (const float*)d_in[6],  (const float*)d_in[7],
        coord, wsf + OFF_FIELD, wsf + OFF_HH);

    for (int l = 0; l < NL; l++) {
        hipMemsetAsync(wsf + OFF_CSUM, 0, (30000 + 640000) * sizeof(float), stream);
        edge_kernel<<<NEBLK, 256, 0, stream>>>(
            rows, cols, wsi + IOFF_PERM,
            coord, wsf + OFF_HH, (const float*)d_in[3],
            ((const float*)d_in[15]) + l * 8384, ((const float*)d_in[16]) + l * 64,
            ((const float*)d_in[17]) + l * 4096, ((const float*)d_in[18]) + l * 64,
            ((const float*)d_in[23]) + l * 4096, ((const float*)d_in[24]) + l * 64,
            ((const float*)d_in[25]) + l * 64,
            wsf + OFF_CSUM, wsf + OFF_MAGG);
        node_kernel<<<NNODEBLK, 256, 0, stream>>>(
            ((const float*)d_in[26]) + l * 4096, ((const float*)d_in[27]) + l * 64,
            ((const float*)d_in[28]) + l * 64,   ((const float*)d_in[29]) + l,
            ((const float*)d_in[30]) + l * 4096, ((const float*)d_in[31]) + l * 64,
            ((const float*)d_in[32]) + l * 64,   ((const float*)d_in[33]) + l,
            ((const float*)d_in[19]) + l * 8192, ((const float*)d_in[20]) + l * 64,
            ((const float*)d_in[21]) + l * 4096, ((const float*)d_in[22]) + l * 64,
            wsf + OFF_CSUM, wsi + IOFF_OFF, (const float*)d_in[2],
            wsf + OFF_FIELD, wsf + OFF_MAGG, coord, wsf + OFF_HH);
    }
}